// Round 4
// baseline (322.217 us; speedup 1.0000x reference)
//
#include <hip/hip_runtime.h>
#include <math.h>

// ---------------------------------------------------------------------------
// HROMAttention: x(4,2048,512) -> QKV(+bias) -> RoPE -> MHA(8 heads, d=64)
//                -> proj(+bias). bf16 MFMA 16x16x32, fp32 accum.
// Round 4 attn: back to LDS staging + register prefetch (R2-proven latency
// hiding), PLUS:
//  - K-row permutation sigma at staging so S^T's C-regs pack directly into
//    PV B-frags (P never touches LDS)
//  - in-block 2-way split-K (4 waves = qsplit2 x ksplit2, 64q blocks,
//    grid 1024 = 4 blocks/CU = 16 waves/CU) with LDS merge
//  - XOR-swizzled unpadded LDS (32 KB), mask folded into MFMA C-init,
//    ones-MFMA row-sum l, exp2-domain softmax, pk_bf16 packing
// ws layout (bytes) — identical to round 2/3.
// ---------------------------------------------------------------------------

typedef __attribute__((ext_vector_type(8))) short bf16x8;
typedef __attribute__((ext_vector_type(4))) float floatx4;

#define LOG2E 1.44269504088896f

__device__ __forceinline__ unsigned short f2bf(float f) {
  unsigned int u = __float_as_uint(f);
  u += 0x7fffu + ((u >> 16) & 1u);   // round-to-nearest-even
  return (unsigned short)(u >> 16);
}

#if defined(__has_builtin)
#if __has_builtin(__builtin_amdgcn_cvt_pk_bf16_f32)
#define HAVE_PK_BF16 1
#endif
#endif

__device__ __forceinline__ unsigned int f2bf2(float a, float b) {
#ifdef HAVE_PK_BF16
  auto v = __builtin_amdgcn_cvt_pk_bf16_f32(a, b);
  union { decltype(v) x; unsigned int u; } c;
  c.x = v;
  return c.u;
#else
  return (unsigned int)f2bf(a) | ((unsigned int)f2bf(b) << 16);
#endif
}

__device__ __forceinline__ void gld_lds16(unsigned short* lds, const unsigned short* g) {
  __builtin_amdgcn_global_load_lds(
      (const __attribute__((address_space(1))) unsigned int*)g,
      (__attribute__((address_space(3))) unsigned int*)lds, 16, 0, 0);
}

// ---------------------------------------------------------------------------
// prep: bf16 conversions + RoPE cos/sin table (fp64 trig for accuracy)
// ---------------------------------------------------------------------------
__global__ __launch_bounds__(256) void prep_kernel(
    const float* __restrict__ x, const float* __restrict__ wq, const float* __restrict__ wp,
    unsigned short* __restrict__ xb, unsigned short* __restrict__ wqb,
    unsigned short* __restrict__ wpb, float* __restrict__ cosT, float* __restrict__ sinT) {
  int i = blockIdx.x * 256 + threadIdx.x;
  if (i < 4194304) {
    xb[i] = f2bf(x[i]);
  } else if (i < 4980736) {
    int j = i - 4194304; wqb[j] = f2bf(wq[j]);
  } else if (i < 5242880) {
    int j = i - 4980736; wpb[j] = f2bf(wp[j]);
  } else if (i < 5308416) {
    int j = i - 5242880;
    int t = j >> 5, f = j & 31;
    double fr = (double)t * pow(10000.0, -(double)f / 32.0);
    cosT[j] = (float)cos(fr);
    sinT[j] = (float)sin(fr);
  }
}

// ---------------------------------------------------------------------------
// QKV GEMM: 128x128 tile, BK=32, 4 waves each 64x64. (unchanged from R3)
// ---------------------------------------------------------------------------
__global__ __launch_bounds__(256) void qkv_kernel(
    const unsigned short* __restrict__ xb, const unsigned short* __restrict__ wqb,
    const float* __restrict__ qkv_b, const float* __restrict__ cosT,
    const float* __restrict__ sinT, unsigned short* __restrict__ Qb,
    unsigned short* __restrict__ Kb, unsigned short* __restrict__ Vtb) {
  __shared__ __align__(16) unsigned short As[128 * 32];
  __shared__ __align__(16) unsigned short Bs[128 * 32];
  const int tid = threadIdx.x;
  const int wave = tid >> 6, lane = tid & 63, ln = lane & 15, quad = lane >> 4;
  const int m0 = blockIdx.x * 128, n0 = blockIdx.y * 128;
  const int wr = (wave >> 1) * 64, wc = (wave & 1) * 64;
  const bool isV = (blockIdx.y >= 8);

  floatx4 acc[4][4];
#pragma unroll
  for (int i = 0; i < 4; ++i)
#pragma unroll
    for (int j = 0; j < 4; ++j) acc[i][j] = (floatx4){0.f, 0.f, 0.f, 0.f};

  const int c0 = tid, c1 = tid + 256;
  const int ar0 = c0 >> 2, ak0 = (c0 & 3) * 8;
  const int ar1 = c1 >> 2, ak1 = (c1 & 3) * 8;

  for (int k0 = 0; k0 < 512; k0 += 32) {
    __syncthreads();
    gld_lds16(As + c0 * 8, xb + (size_t)(m0 + ar0) * 512 + k0 + ak0);
    gld_lds16(As + c1 * 8, xb + (size_t)(m0 + ar1) * 512 + k0 + ak1);
    gld_lds16(Bs + c0 * 8, wqb + (size_t)(n0 + ar0) * 512 + k0 + ak0);
    gld_lds16(Bs + c1 * 8, wqb + (size_t)(n0 + ar1) * 512 + k0 + ak1);
    __syncthreads();
    bf16x8 af[4], bfb[4];
#pragma unroll
    for (int mi = 0; mi < 4; ++mi)
      af[mi] = *(const bf16x8*)(As + (wr + mi * 16 + ln) * 32 + quad * 8);
#pragma unroll
    for (int ni = 0; ni < 4; ++ni)
      bfb[ni] = *(const bf16x8*)(Bs + (wc + ni * 16 + ln) * 32 + quad * 8);
    if (isV) {
#pragma unroll
      for (int mi = 0; mi < 4; ++mi)
#pragma unroll
        for (int ni = 0; ni < 4; ++ni)
          acc[mi][ni] = __builtin_amdgcn_mfma_f32_16x16x32_bf16(af[mi], bfb[ni], acc[mi][ni], 0, 0, 0);
    } else {
#pragma unroll
      for (int mi = 0; mi < 4; ++mi)
#pragma unroll
        for (int ni = 0; ni < 4; ++ni)
          acc[mi][ni] = __builtin_amdgcn_mfma_f32_16x16x32_bf16(bfb[mi], af[ni], acc[mi][ni], 0, 0, 0);
    }
  }

  const int colbase = n0 + wc;
  const int mat = colbase >> 9;
  const int h = (colbase & 511) >> 6;

  if (isV) {
    float bias[4];
#pragma unroll
    for (int ni = 0; ni < 4; ++ni) bias[ni] = qkv_b[colbase + ni * 16 + ln];
#pragma unroll
    for (int mi = 0; mi < 4; ++mi) {
      int row0 = m0 + wr + mi * 16 + quad * 4;
      int bidx = row0 >> 11, t = row0 & 2047;
#pragma unroll
      for (int ni = 0; ni < 4; ++ni) {
        int d = ni * 16 + ln;
        unsigned int u0 = f2bf2(acc[mi][ni][0] + bias[ni], acc[mi][ni][1] + bias[ni]);
        unsigned int u1 = f2bf2(acc[mi][ni][2] + bias[ni], acc[mi][ni][3] + bias[ni]);
        *(uint2*)(Vtb + ((size_t)(bidx * 8 + h) * 64 + d) * 2048 + t) = make_uint2(u0, u1);
      }
    }
  } else {
    unsigned short* dst = (mat == 0) ? Qb : Kb;
    const float sc = (mat == 0) ? 0.125f * LOG2E : 1.0f;
    float4 blo[2], bhi[2];
#pragma unroll
    for (int mi = 0; mi < 2; ++mi) {
      blo[mi] = *(const float4*)(qkv_b + colbase + mi * 16 + quad * 4);
      bhi[mi] = *(const float4*)(qkv_b + colbase + 32 + mi * 16 + quad * 4);
    }
#pragma unroll
    for (int ni = 0; ni < 4; ++ni) {
      int row = m0 + wr + ni * 16 + ln;
      int bidx = row >> 11, t = row & 2047;
      unsigned short* tb = dst + ((size_t)(bidx * 8 + h) * 2048 + t) * 64;
#pragma unroll
      for (int mi = 0; mi < 2; ++mi) {
        int dbase = mi * 16 + quad * 4;
        float4 c4 = *(const float4*)(cosT + t * 32 + dbase);
        float4 s4 = *(const float4*)(sinT + t * 32 + dbase);
        float xl0 = acc[mi][ni][0] + blo[mi].x, xh0 = acc[mi + 2][ni][0] + bhi[mi].x;
        float xl1 = acc[mi][ni][1] + blo[mi].y, xh1 = acc[mi + 2][ni][1] + bhi[mi].y;
        float xl2 = acc[mi][ni][2] + blo[mi].z, xh2 = acc[mi + 2][ni][2] + bhi[mi].z;
        float xl3 = acc[mi][ni][3] + blo[mi].w, xh3 = acc[mi + 2][ni][3] + bhi[mi].w;
        unsigned int lo01 = f2bf2((xl0 * c4.x - xh0 * s4.x) * sc, (xl1 * c4.y - xh1 * s4.y) * sc);
        unsigned int lo23 = f2bf2((xl2 * c4.z - xh2 * s4.z) * sc, (xl3 * c4.w - xh3 * s4.w) * sc);
        unsigned int hi01 = f2bf2((xh0 * c4.x + xl0 * s4.x) * sc, (xh1 * c4.y + xl1 * s4.y) * sc);
        unsigned int hi23 = f2bf2((xh2 * c4.z + xl2 * s4.z) * sc, (xh3 * c4.w + xl3 * s4.w) * sc);
        *(uint2*)(tb + dbase) = make_uint2(lo01, lo23);
        *(uint2*)(tb + 32 + dbase) = make_uint2(hi01, hi23);
      }
    }
  }
}

// ---------------------------------------------------------------------------
// Flash attention R4. Block 256 thr = 4 waves = (qsplit 2)x(ksplit 2); block
// covers 64 q; wave(qi,ki) does q0+qi*32, k in [ki*1024,(ki+1)*1024).
// K staged with row-permutation sigma: LDS row s holds global K row tperm(s)
//   tperm(s): t5=s5, t4=s3, t3=s2, t2=s4, t1=s1, t0=s0
// so S^T C-regs (t_k = tile*16+quad*4+r) pack DIRECTLY into PV B-frag slots
// (k = quad*8 + 4*(tile&1) + r, tile pair -> one 16x16x32 B-frag). P never
// touches LDS. V staged naturally. XOR-swizzle: 16B-chunk c stored at
// c ^ (row&7), stride 64 shorts.
// ---------------------------------------------------------------------------
__global__ __launch_bounds__(256, 4) void attn_kernel(
    const unsigned short* __restrict__ Qb, const unsigned short* __restrict__ Kb,
    const unsigned short* __restrict__ Vtb, const float* __restrict__ mask,
    unsigned short* __restrict__ attnb) {
  __shared__ __align__(16) unsigned short smem[16384];  // 32 KB

  const int tid = threadIdx.x;
  const int wave = tid >> 6, lane = tid & 63, ln = lane & 15, quad = lane >> 4;
  const int qi = wave & 1, ki = wave >> 1;
  const int bh = blockIdx.y, b = bh >> 3, h = bh & 7;
  const int q0 = blockIdx.x * 64 + qi * 32;
  const int kbeg = ki * 1024, kend = kbeg + 1024;

  const unsigned short* Qhead = Qb + (size_t)bh * 2048 * 64;
  const unsigned short* Khead = Kb + (size_t)bh * 2048 * 64;
  const unsigned short* Vhead = Vtb + (size_t)bh * 64 * 2048;
  unsigned short* Ks = smem + ki * 4096;
  unsigned short* Vs = smem + 8192 + ki * 4096;

  // ---- staging map (pair-local p in [0,128)): 4 passes x 16 B ----
  const int p = tid & 127;
  int offK[4], offV[4], vgrow[4];
#pragma unroll
  for (int i = 0; i < 4; ++i) {
    int g = i * 16 + (p >> 3);        // global row (K: t_k-local; V: d)
    int c = p & 7;                    // 16B chunk within row
    int s = (g & 0x23) | ((g & 4) << 2) | ((g & 16) >> 1) | ((g & 8) >> 1);  // sigma(g)
    offK[i] = s * 64 + ((c ^ (s & 7)) << 3);
    offV[i] = g * 64 + ((c ^ (g & 7)) << 3);
    vgrow[i] = g;
  }

  // Q B-frags (B[n=q][k=d]), loaded once
  bf16x8 qf[2][2];
#pragma unroll
  for (int ni2 = 0; ni2 < 2; ++ni2)
#pragma unroll
    for (int ks = 0; ks < 2; ++ks)
      qf[ni2][ks] = *(const bf16x8*)(Qhead + (size_t)(q0 + ni2 * 16 + ln) * 64 + ks * 32 + quad * 8);

  bf16x8 ones;
#pragma unroll
  for (int j = 0; j < 8; ++j) ones[j] = (short)0x3F80;

  floatx4 o[4][2];   // O^T: [d-tile][q-tile]
#pragma unroll
  for (int mi2 = 0; mi2 < 4; ++mi2)
#pragma unroll
    for (int ni2 = 0; ni2 < 2; ++ni2) o[mi2][ni2] = (floatx4){0.f, 0.f, 0.f, 0.f};
  floatx4 o5[2] = {(floatx4){0.f, 0.f, 0.f, 0.f}, (floatx4){0.f, 0.f, 0.f, 0.f}};
  float mrun[2] = {-INFINITY, -INFINITY};

  // initial prefetch
  uint4 kpre[4], vpre[4];
#pragma unroll
  for (int i = 0; i < 4; ++i) {
    kpre[i] = *(const uint4*)(Khead + (size_t)kbeg * 64 + i * 1024 + p * 8);
    vpre[i] = *(const uint4*)(Vhead + (size_t)vgrow[i] * 2048 + kbeg + (p & 7) * 8);
  }

  for (int k0 = kbeg; k0 < kend; k0 += 64) {
    __syncthreads();
#pragma unroll
    for (int i = 0; i < 4; ++i) {
      *(uint4*)(Ks + offK[i]) = kpre[i];
      *(uint4*)(Vs + offV[i]) = vpre[i];
    }
    __syncthreads();

    // mask -> C-init at permuted row addresses (t_k = 32*(mi>>1)+4*(mi&1)+8*quad+r)
    floatx4 cini[4];
#pragma unroll
    for (int mi = 0; mi < 4; ++mi) {
      float4 mv = *(const float4*)(mask + b * 2048 + k0 + 32 * (mi >> 1) + 4 * (mi & 1) + 8 * quad);
      cini[mi] = (floatx4){mv.x * LOG2E, mv.y * LOG2E, mv.z * LOG2E, mv.w * LOG2E};
    }
    // S^T = K·Q^T from swizzled LDS
    floatx4 sm[4][2];
#pragma unroll
    for (int mi = 0; mi < 4; ++mi) {
      int row = mi * 16 + ln;
      bf16x8 kf0 = *(const bf16x8*)(Ks + row * 64 + ((quad ^ (ln & 7)) << 3));
      bf16x8 kf1 = *(const bf16x8*)(Ks + row * 64 + (((4 + quad) ^ (ln & 7)) << 3));
#pragma unroll
      for (int ni2 = 0; ni2 < 2; ++ni2) {
        floatx4 a = cini[mi];
        a = __builtin_amdgcn_mfma_f32_16x16x32_bf16(kf0, qf[ni2][0], a, 0, 0, 0);
        a = __builtin_amdgcn_mfma_f32_16x16x32_bf16(kf1, qf[ni2][1], a, 0, 0, 0);
        sm[mi][ni2] = a;
      }
    }
    // online softmax (per lane one q-col; combine quads with 2 shuffles)
    float alpha[2];
#pragma unroll
    for (int ni2 = 0; ni2 < 2; ++ni2) {
      float vmax = fmaxf(fmaxf(sm[0][ni2][0], sm[0][ni2][1]), fmaxf(sm[0][ni2][2], sm[0][ni2][3]));
#pragma unroll
      for (int mi = 1; mi < 4; ++mi)
        vmax = fmaxf(vmax, fmaxf(fmaxf(sm[mi][ni2][0], sm[mi][ni2][1]),
                                 fmaxf(sm[mi][ni2][2], sm[mi][ni2][3])));
      vmax = fmaxf(vmax, __shfl_xor(vmax, 16));
      vmax = fmaxf(vmax, __shfl_xor(vmax, 32));
      float nm = fmaxf(mrun[ni2], vmax);
      alpha[ni2] = exp2f(mrun[ni2] - nm);
      mrun[ni2] = nm;
    }
#pragma unroll
    for (int mi2 = 0; mi2 < 4; ++mi2)
#pragma unroll
      for (int ni2 = 0; ni2 < 2; ++ni2) {
        o[mi2][ni2][0] *= alpha[ni2]; o[mi2][ni2][1] *= alpha[ni2];
        o[mi2][ni2][2] *= alpha[ni2]; o[mi2][ni2][3] *= alpha[ni2];
      }
#pragma unroll
    for (int ni2 = 0; ni2 < 2; ++ni2) {
      o5[ni2][0] *= alpha[ni2]; o5[ni2][1] *= alpha[ni2];
      o5[ni2][2] *= alpha[ni2]; o5[ni2][3] *= alpha[ni2];
    }
    // p = exp2(s-m); pack straight into PV B-frags (tiles 2ks,2ks+1 -> one frag)
    bf16x8 pb[2][2];   // [ni2][ks]
#pragma unroll
    for (int ks = 0; ks < 2; ++ks)
#pragma unroll
      for (int ni2 = 0; ni2 < 2; ++ni2) {
        union { bf16x8 v; unsigned int u[4]; } pk;
        pk.u[0] = f2bf2(exp2f(sm[2 * ks][ni2][0] - mrun[ni2]), exp2f(sm[2 * ks][ni2][1] - mrun[ni2]));
        pk.u[1] = f2bf2(exp2f(sm[2 * ks][ni2][2] - mrun[ni2]), exp2f(sm[2 * ks][ni2][3] - mrun[ni2]));
        pk.u[2] = f2bf2(exp2f(sm[2 * ks + 1][ni2][0] - mrun[ni2]), exp2f(sm[2 * ks + 1][ni2][1] - mrun[ni2]));
        pk.u[3] = f2bf2(exp2f(sm[2 * ks + 1][ni2][2] - mrun[ni2]), exp2f(sm[2 * ks + 1][ni2][3] - mrun[ni2]));
        pb[ni2][ks] = pk.v;
      }
    // prefetch next tile (issued before PV so latency hides under MFMA)
    if (k0 + 64 < kend) {
#pragma unroll
      for (int i = 0; i < 4; ++i) {
        kpre[i] = *(const uint4*)(Khead + (size_t)(k0 + 64) * 64 + i * 1024 + p * 8);
        vpre[i] = *(const uint4*)(Vhead + (size_t)vgrow[i] * 2048 + (k0 + 64) + (p & 7) * 8);
      }
    }
    // O^T += V^T·P ; l += ones·P
#pragma unroll
    for (int ks = 0; ks < 2; ++ks) {
#pragma unroll
      for (int mi2 = 0; mi2 < 4; ++mi2) {
        int row = mi2 * 16 + ln;
        bf16x8 vf = *(const bf16x8*)(Vs + row * 64 + (((ks * 4 + quad) ^ (ln & 7)) << 3));
#pragma unroll
        for (int ni2 = 0; ni2 < 2; ++ni2)
          o[mi2][ni2] = __builtin_amdgcn_mfma_f32_16x16x32_bf16(vf, pb[ni2][ks], o[mi2][ni2], 0, 0, 0);
      }
#pragma unroll
      for (int ni2 = 0; ni2 < 2; ++ni2)
        o5[ni2] = __builtin_amdgcn_mfma_f32_16x16x32_bf16(ones, pb[ni2][ks], o5[ni2], 0, 0, 0);
    }
  }

  // ---- split-K merge: ki=0 waves -> LDS scratch, ki=1 waves combine+store ----
  __syncthreads();                     // all staging-buffer reads done
  float* scr = (float*)smem;           // 2 waves x 64 lanes x 40 floats = 20 KB
  const int base = (qi * 64 + lane) * 40;
  if (ki == 0) {
#pragma unroll
    for (int mi2 = 0; mi2 < 4; ++mi2)
#pragma unroll
      for (int ni2 = 0; ni2 < 2; ++ni2)
        *(floatx4*)(scr + base + (mi2 * 2 + ni2) * 4) = o[mi2][ni2];
    scr[base + 32] = mrun[0];
    scr[base + 33] = mrun[1];
    scr[base + 34] = o5[0][0];
    scr[base + 35] = o5[1][0];
  }
  __syncthreads();
  if (ki == 1) {
#pragma unroll
    for (int ni2 = 0; ni2 < 2; ++ni2) {
      float m0s = scr[base + 32 + ni2];
      float l0s = scr[base + 34 + ni2];
      float M = fmaxf(m0s, mrun[ni2]);
      float c0 = exp2f(m0s - M);
      float c1 = exp2f(mrun[ni2] - M);
      float inv = 1.f / (l0s * c0 + o5[ni2][0] * c1);
      float ic0 = c0 * inv, ic1 = c1 * inv;
      int t = q0 + ni2 * 16 + ln;
      size_t obase = ((size_t)b * 2048 + t) * 512 + h * 64;
#pragma unroll
      for (int mi2 = 0; mi2 < 4; ++mi2) {
        floatx4 p0 = *(const floatx4*)(scr + base + (mi2 * 2 + ni2) * 4);
        unsigned int u0 = f2bf2(p0[0] * ic0 + o[mi2][ni2][0] * ic1,
                                p0[1] * ic0 + o[mi2][ni2][1] * ic1);
        unsigned int u1 = f2bf2(p0[2] * ic0 + o[mi2][ni2][2] * ic1,
                                p0[3] * ic0 + o[mi2][ni2][3] * ic1);
        *(uint2*)(attnb + obase + mi2 * 16 + quad * 4) = make_uint2(u0, u1);
      }
    }
  }
}

// ---------------------------------------------------------------------------
// proj GEMM (swapped operands), unchanged from R3
// ---------------------------------------------------------------------------
__global__ __launch_bounds__(256) void proj_kernel(
    const unsigned short* __restrict__ ab, const unsigned short* __restrict__ wpb,
    const float* __restrict__ proj_b, float* __restrict__ out) {
  __shared__ __align__(16) unsigned short As[128 * 32];
  __shared__ __align__(16) unsigned short Bs[128 * 32];
  const int tid = threadIdx.x;
  const int wave = tid >> 6, lane = tid & 63, ln = lane & 15, quad = lane >> 4;
  const int m0 = blockIdx.x * 128, n0 = blockIdx.y * 128;
  const int wr = (wave >> 1) * 64, wc = (wave & 1) * 64;

  floatx4 acc[4][4];
#pragma unroll
  for (int i = 0; i < 4; ++i)
#pragma unroll
    for (int j = 0; j < 4; ++j) acc[i][j] = (floatx4){0.f, 0.f, 0.f, 0.f};

  const int c0 = tid, c1 = tid + 256;
  const int ar0 = c0 >> 2, ak0 = (c0 & 3) * 8;
  const int ar1 = c1 >> 2, ak1 = (c1 & 3) * 8;

  for (int k0 = 0; k0 < 512; k0 += 32) {
    __syncthreads();
    gld_lds16(As + c0 * 8, ab + (size_t)(m0 + ar0) * 512 + k0 + ak0);
    gld_lds16(As + c1 * 8, ab + (size_t)(m0 + ar1) * 512 + k0 + ak1);
    gld_lds16(Bs + c0 * 8, wpb + (size_t)(n0 + ar0) * 512 + k0 + ak0);
    gld_lds16(Bs + c1 * 8, wpb + (size_t)(n0 + ar1) * 512 + k0 + ak1);
    __syncthreads();
    bf16x8 af[4], bfb[4];
#pragma unroll
    for (int mi = 0; mi < 4; ++mi)
      af[mi] = *(const bf16x8*)(As + (wr + mi * 16 + ln) * 32 + quad * 8);
#pragma unroll
    for (int ni = 0; ni < 4; ++ni)
      bfb[ni] = *(const bf16x8*)(Bs + (wc + ni * 16 + ln) * 32 + quad * 8);
#pragma unroll
    for (int mi = 0; mi < 4; ++mi)
#pragma unroll
      for (int ni = 0; ni < 4; ++ni)
        acc[mi][ni] = __builtin_amdgcn_mfma_f32_16x16x32_bf16(bfb[mi], af[ni], acc[mi][ni], 0, 0, 0);
  }

  float4 bias4[4];
#pragma unroll
  for (int mi = 0; mi < 4; ++mi)
    bias4[mi] = *(const float4*)(proj_b + n0 + wc + mi * 16 + quad * 4);
#pragma unroll
  for (int ni = 0; ni < 4; ++ni) {
    int t = m0 + wr + ni * 16 + ln;
#pragma unroll
    for (int mi = 0; mi < 4; ++mi) {
      int col = n0 + wc + mi * 16 + quad * 4;
      float4 st;
      st.x = acc[mi][ni][0] + bias4[mi].x;
      st.y = acc[mi][ni][1] + bias4[mi].y;
      st.z = acc[mi][ni][2] + bias4[mi].z;
      st.w = acc[mi][ni][3] + bias4[mi].w;
      *(float4*)(out + (size_t)t * 512 + col) = st;
    }
  }
}

// ---------------------------------------------------------------------------
extern "C" void kernel_launch(void* const* d_in, const int* in_sizes, int n_in,
                              void* d_out, int out_size, void* d_ws, size_t ws_size,
                              hipStream_t stream) {
  const float* x      = (const float*)d_in[0];
  const float* mask   = (const float*)d_in[1];
  const float* qkv_w  = (const float*)d_in[2];
  const float* qkv_b  = (const float*)d_in[3];
  const float* proj_w = (const float*)d_in[4];
  const float* proj_b = (const float*)d_in[5];
  float* out = (float*)d_out;

  char* ws = (char*)d_ws;
  unsigned short* xb   = (unsigned short*)(ws);
  unsigned short* wqb  = (unsigned short*)(ws + 8388608);
  unsigned short* wpb  = (unsigned short*)(ws + 9961472);
  float* cosT          = (float*)(ws + 10485760);
  float* sinT          = (float*)(ws + 10747904);
  unsigned short* Qb   = (unsigned short*)(ws + 11010048);
  unsigned short* Kb   = (unsigned short*)(ws + 19398656);
  unsigned short* Vtb  = (unsigned short*)(ws + 27787264);
  unsigned short* attnb= (unsigned short*)(ws + 36175872);

  prep_kernel<<<20736, 256, 0, stream>>>(x, qkv_w, proj_w, xb, wqb, wpb, cosT, sinT);
  dim3 g1(64, 12);
  qkv_kernel<<<g1, 256, 0, stream>>>(xb, wqb, qkv_b, cosT, sinT, Qb, Kb, Vtb);
  dim3 g2(32, 32);
  attn_kernel<<<g2, 256, 0, stream>>>(Qb, Kb, Vtb, mask, attnb);
  dim3 g3(64, 4);
  proj_kernel<<<g3, 256, 0, stream>>>(attnb, wpb, proj_b, out);
}

// Round 5
// 315.414 us; speedup vs baseline: 1.0216x; 1.0216x over previous
//
#include <hip/hip_runtime.h>
#include <math.h>

// ---------------------------------------------------------------------------
// HROMAttention: x(4,2048,512) -> QKV(+bias) -> RoPE -> MHA(8 heads, d=64)
//                -> proj(+bias). bf16 MFMA 16x16x32, fp32 accum.
// Round 5 = Round 4 with the spill fixed: attn __launch_bounds__(256,2).
// R4's (256,4) demanded <=128 VGPRs for a ~160-VGPR live set -> compiler
// spilled hot-loop accumulators to scratch (HBM): WRITE_SIZE 537 MB.
// (256,2) caps at 256 VGPRs: no spill; occupancy set by actual alloc (~160
// VGPR -> 3 waves/SIMD).
// attn structure (verified correct in R4):
//  - K-row permutation sigma at staging so S^T's C-regs pack directly into
//    PV B-frags (P never touches LDS)
//  - in-block 2-way split-K (4 waves = qsplit2 x ksplit2, 64q blocks) + merge
//  - XOR-swizzled unpadded LDS (32 KB), mask folded into MFMA C-init,
//    ones-MFMA row-sum l, exp2-domain softmax, pk_bf16 packing,
//    register prefetch of K/V staging loads
// ---------------------------------------------------------------------------

typedef __attribute__((ext_vector_type(8))) short bf16x8;
typedef __attribute__((ext_vector_type(4))) float floatx4;

#define LOG2E 1.44269504088896f

__device__ __forceinline__ unsigned short f2bf(float f) {
  unsigned int u = __float_as_uint(f);
  u += 0x7fffu + ((u >> 16) & 1u);   // round-to-nearest-even
  return (unsigned short)(u >> 16);
}

#if defined(__has_builtin)
#if __has_builtin(__builtin_amdgcn_cvt_pk_bf16_f32)
#define HAVE_PK_BF16 1
#endif
#endif

__device__ __forceinline__ unsigned int f2bf2(float a, float b) {
#ifdef HAVE_PK_BF16
  auto v = __builtin_amdgcn_cvt_pk_bf16_f32(a, b);
  union { decltype(v) x; unsigned int u; } c;
  c.x = v;
  return c.u;
#else
  return (unsigned int)f2bf(a) | ((unsigned int)f2bf(b) << 16);
#endif
}

__device__ __forceinline__ void gld_lds16(unsigned short* lds, const unsigned short* g) {
  __builtin_amdgcn_global_load_lds(
      (const __attribute__((address_space(1))) unsigned int*)g,
      (__attribute__((address_space(3))) unsigned int*)lds, 16, 0, 0);
}

// ---------------------------------------------------------------------------
// prep: bf16 conversions + RoPE cos/sin table (fp64 trig for accuracy)
// ---------------------------------------------------------------------------
__global__ __launch_bounds__(256) void prep_kernel(
    const float* __restrict__ x, const float* __restrict__ wq, const float* __restrict__ wp,
    unsigned short* __restrict__ xb, unsigned short* __restrict__ wqb,
    unsigned short* __restrict__ wpb, float* __restrict__ cosT, float* __restrict__ sinT) {
  int i = blockIdx.x * 256 + threadIdx.x;
  if (i < 4194304) {
    xb[i] = f2bf(x[i]);
  } else if (i < 4980736) {
    int j = i - 4194304; wqb[j] = f2bf(wq[j]);
  } else if (i < 5242880) {
    int j = i - 4980736; wpb[j] = f2bf(wp[j]);
  } else if (i < 5308416) {
    int j = i - 5242880;
    int t = j >> 5, f = j & 31;
    double fr = (double)t * pow(10000.0, -(double)f / 32.0);
    cosT[j] = (float)cos(fr);
    sinT[j] = (float)sin(fr);
  }
}

// ---------------------------------------------------------------------------
// QKV GEMM: 128x128 tile, BK=32, 4 waves each 64x64. (unchanged)
// ---------------------------------------------------------------------------
__global__ __launch_bounds__(256) void qkv_kernel(
    const unsigned short* __restrict__ xb, const unsigned short* __restrict__ wqb,
    const float* __restrict__ qkv_b, const float* __restrict__ cosT,
    const float* __restrict__ sinT, unsigned short* __restrict__ Qb,
    unsigned short* __restrict__ Kb, unsigned short* __restrict__ Vtb) {
  __shared__ __align__(16) unsigned short As[128 * 32];
  __shared__ __align__(16) unsigned short Bs[128 * 32];
  const int tid = threadIdx.x;
  const int wave = tid >> 6, lane = tid & 63, ln = lane & 15, quad = lane >> 4;
  const int m0 = blockIdx.x * 128, n0 = blockIdx.y * 128;
  const int wr = (wave >> 1) * 64, wc = (wave & 1) * 64;
  const bool isV = (blockIdx.y >= 8);

  floatx4 acc[4][4];
#pragma unroll
  for (int i = 0; i < 4; ++i)
#pragma unroll
    for (int j = 0; j < 4; ++j) acc[i][j] = (floatx4){0.f, 0.f, 0.f, 0.f};

  const int c0 = tid, c1 = tid + 256;
  const int ar0 = c0 >> 2, ak0 = (c0 & 3) * 8;
  const int ar1 = c1 >> 2, ak1 = (c1 & 3) * 8;

  for (int k0 = 0; k0 < 512; k0 += 32) {
    __syncthreads();
    gld_lds16(As + c0 * 8, xb + (size_t)(m0 + ar0) * 512 + k0 + ak0);
    gld_lds16(As + c1 * 8, xb + (size_t)(m0 + ar1) * 512 + k0 + ak1);
    gld_lds16(Bs + c0 * 8, wqb + (size_t)(n0 + ar0) * 512 + k0 + ak0);
    gld_lds16(Bs + c1 * 8, wqb + (size_t)(n0 + ar1) * 512 + k0 + ak1);
    __syncthreads();
    bf16x8 af[4], bfb[4];
#pragma unroll
    for (int mi = 0; mi < 4; ++mi)
      af[mi] = *(const bf16x8*)(As + (wr + mi * 16 + ln) * 32 + quad * 8);
#pragma unroll
    for (int ni = 0; ni < 4; ++ni)
      bfb[ni] = *(const bf16x8*)(Bs + (wc + ni * 16 + ln) * 32 + quad * 8);
    if (isV) {
#pragma unroll
      for (int mi = 0; mi < 4; ++mi)
#pragma unroll
        for (int ni = 0; ni < 4; ++ni)
          acc[mi][ni] = __builtin_amdgcn_mfma_f32_16x16x32_bf16(af[mi], bfb[ni], acc[mi][ni], 0, 0, 0);
    } else {
#pragma unroll
      for (int mi = 0; mi < 4; ++mi)
#pragma unroll
        for (int ni = 0; ni < 4; ++ni)
          acc[mi][ni] = __builtin_amdgcn_mfma_f32_16x16x32_bf16(bfb[mi], af[ni], acc[mi][ni], 0, 0, 0);
    }
  }

  const int colbase = n0 + wc;
  const int mat = colbase >> 9;
  const int h = (colbase & 511) >> 6;

  if (isV) {
    float bias[4];
#pragma unroll
    for (int ni = 0; ni < 4; ++ni) bias[ni] = qkv_b[colbase + ni * 16 + ln];
#pragma unroll
    for (int mi = 0; mi < 4; ++mi) {
      int row0 = m0 + wr + mi * 16 + quad * 4;
      int bidx = row0 >> 11, t = row0 & 2047;
#pragma unroll
      for (int ni = 0; ni < 4; ++ni) {
        int d = ni * 16 + ln;
        unsigned int u0 = f2bf2(acc[mi][ni][0] + bias[ni], acc[mi][ni][1] + bias[ni]);
        unsigned int u1 = f2bf2(acc[mi][ni][2] + bias[ni], acc[mi][ni][3] + bias[ni]);
        *(uint2*)(Vtb + ((size_t)(bidx * 8 + h) * 64 + d) * 2048 + t) = make_uint2(u0, u1);
      }
    }
  } else {
    unsigned short* dst = (mat == 0) ? Qb : Kb;
    const float sc = (mat == 0) ? 0.125f * LOG2E : 1.0f;
    float4 blo[2], bhi[2];
#pragma unroll
    for (int mi = 0; mi < 2; ++mi) {
      blo[mi] = *(const float4*)(qkv_b + colbase + mi * 16 + quad * 4);
      bhi[mi] = *(const float4*)(qkv_b + colbase + 32 + mi * 16 + quad * 4);
    }
#pragma unroll
    for (int ni = 0; ni < 4; ++ni) {
      int row = m0 + wr + ni * 16 + ln;
      int bidx = row >> 11, t = row & 2047;
      unsigned short* tb = dst + ((size_t)(bidx * 8 + h) * 2048 + t) * 64;
#pragma unroll
      for (int mi = 0; mi < 2; ++mi) {
        int dbase = mi * 16 + quad * 4;
        float4 c4 = *(const float4*)(cosT + t * 32 + dbase);
        float4 s4 = *(const float4*)(sinT + t * 32 + dbase);
        float xl0 = acc[mi][ni][0] + blo[mi].x, xh0 = acc[mi + 2][ni][0] + bhi[mi].x;
        float xl1 = acc[mi][ni][1] + blo[mi].y, xh1 = acc[mi + 2][ni][1] + bhi[mi].y;
        float xl2 = acc[mi][ni][2] + blo[mi].z, xh2 = acc[mi + 2][ni][2] + bhi[mi].z;
        float xl3 = acc[mi][ni][3] + blo[mi].w, xh3 = acc[mi + 2][ni][3] + bhi[mi].w;
        unsigned int lo01 = f2bf2((xl0 * c4.x - xh0 * s4.x) * sc, (xl1 * c4.y - xh1 * s4.y) * sc);
        unsigned int lo23 = f2bf2((xl2 * c4.z - xh2 * s4.z) * sc, (xl3 * c4.w - xh3 * s4.w) * sc);
        unsigned int hi01 = f2bf2((xh0 * c4.x + xl0 * s4.x) * sc, (xh1 * c4.y + xl1 * s4.y) * sc);
        unsigned int hi23 = f2bf2((xh2 * c4.z + xl2 * s4.z) * sc, (xh3 * c4.w + xl3 * s4.w) * sc);
        *(uint2*)(tb + dbase) = make_uint2(lo01, lo23);
        *(uint2*)(tb + 32 + dbase) = make_uint2(hi01, hi23);
      }
    }
  }
}

// ---------------------------------------------------------------------------
// Flash attention R5 (= R4 logic, launch_bounds(256,2) — no spill).
// Block 256 thr = 4 waves = (qsplit 2)x(ksplit 2); block covers 64 q; wave
// (qi,ki) does q0+qi*32, k in [ki*1024,(ki+1)*1024).
// K staged with row-permutation sigma so S^T C-regs pack directly into PV
// B-frags; P never touches LDS. XOR-swizzled unpadded LDS.
// ---------------------------------------------------------------------------
__global__ __launch_bounds__(256, 2) void attn_kernel(
    const unsigned short* __restrict__ Qb, const unsigned short* __restrict__ Kb,
    const unsigned short* __restrict__ Vtb, const float* __restrict__ mask,
    unsigned short* __restrict__ attnb) {
  __shared__ __align__(16) unsigned short smem[16384];  // 32 KB

  const int tid = threadIdx.x;
  const int wave = tid >> 6, lane = tid & 63, ln = lane & 15, quad = lane >> 4;
  const int qi = wave & 1, ki = wave >> 1;
  const int bh = blockIdx.y, b = bh >> 3, h = bh & 7;
  const int q0 = blockIdx.x * 64 + qi * 32;
  const int kbeg = ki * 1024, kend = kbeg + 1024;

  const unsigned short* Qhead = Qb + (size_t)bh * 2048 * 64;
  const unsigned short* Khead = Kb + (size_t)bh * 2048 * 64;
  const unsigned short* Vhead = Vtb + (size_t)bh * 64 * 2048;
  unsigned short* Ks = smem + ki * 4096;
  unsigned short* Vs = smem + 8192 + ki * 4096;

  // ---- staging map (pair-local p in [0,128)): 4 passes x 16 B ----
  const int p = tid & 127;
  int offK[4], offV[4], vgrow[4];
#pragma unroll
  for (int i = 0; i < 4; ++i) {
    int g = i * 16 + (p >> 3);        // global row (K: t_k-local; V: d)
    int c = p & 7;                    // 16B chunk within row
    int s = (g & 0x23) | ((g & 4) << 2) | ((g & 16) >> 1) | ((g & 8) >> 1);  // sigma(g)
    offK[i] = s * 64 + ((c ^ (s & 7)) << 3);
    offV[i] = g * 64 + ((c ^ (g & 7)) << 3);
    vgrow[i] = g;
  }

  // Q B-frags (B[n=q][k=d]), loaded once
  bf16x8 qf[2][2];
#pragma unroll
  for (int ni2 = 0; ni2 < 2; ++ni2)
#pragma unroll
    for (int ks = 0; ks < 2; ++ks)
      qf[ni2][ks] = *(const bf16x8*)(Qhead + (size_t)(q0 + ni2 * 16 + ln) * 64 + ks * 32 + quad * 8);

  bf16x8 ones;
#pragma unroll
  for (int j = 0; j < 8; ++j) ones[j] = (short)0x3F80;

  floatx4 o[4][2];   // O^T: [d-tile][q-tile]
#pragma unroll
  for (int mi2 = 0; mi2 < 4; ++mi2)
#pragma unroll
    for (int ni2 = 0; ni2 < 2; ++ni2) o[mi2][ni2] = (floatx4){0.f, 0.f, 0.f, 0.f};
  floatx4 o5[2] = {(floatx4){0.f, 0.f, 0.f, 0.f}, (floatx4){0.f, 0.f, 0.f, 0.f}};
  float mrun[2] = {-INFINITY, -INFINITY};

  // initial prefetch
  uint4 kpre[4], vpre[4];
#pragma unroll
  for (int i = 0; i < 4; ++i) {
    kpre[i] = *(const uint4*)(Khead + (size_t)kbeg * 64 + i * 1024 + p * 8);
    vpre[i] = *(const uint4*)(Vhead + (size_t)vgrow[i] * 2048 + kbeg + (p & 7) * 8);
  }

  for (int k0 = kbeg; k0 < kend; k0 += 64) {
    __syncthreads();
#pragma unroll
    for (int i = 0; i < 4; ++i) {
      *(uint4*)(Ks + offK[i]) = kpre[i];
      *(uint4*)(Vs + offV[i]) = vpre[i];
    }
    __syncthreads();

    // mask -> C-init at permuted row addresses (t_k = 32*(mi>>1)+4*(mi&1)+8*quad+r)
    floatx4 cini[4];
#pragma unroll
    for (int mi = 0; mi < 4; ++mi) {
      float4 mv = *(const float4*)(mask + b * 2048 + k0 + 32 * (mi >> 1) + 4 * (mi & 1) + 8 * quad);
      cini[mi] = (floatx4){mv.x * LOG2E, mv.y * LOG2E, mv.z * LOG2E, mv.w * LOG2E};
    }
    // S^T = K·Q^T from swizzled LDS
    floatx4 sm[4][2];
#pragma unroll
    for (int mi = 0; mi < 4; ++mi) {
      int row = mi * 16 + ln;
      bf16x8 kf0 = *(const bf16x8*)(Ks + row * 64 + ((quad ^ (ln & 7)) << 3));
      bf16x8 kf1 = *(const bf16x8*)(Ks + row * 64 + (((4 + quad) ^ (ln & 7)) << 3));
#pragma unroll
      for (int ni2 = 0; ni2 < 2; ++ni2) {
        floatx4 a = cini[mi];
        a = __builtin_amdgcn_mfma_f32_16x16x32_bf16(kf0, qf[ni2][0], a, 0, 0, 0);
        a = __builtin_amdgcn_mfma_f32_16x16x32_bf16(kf1, qf[ni2][1], a, 0, 0, 0);
        sm[mi][ni2] = a;
      }
    }
    // online softmax (per lane one q-col; combine quads with 2 shuffles)
    float alpha[2];
#pragma unroll
    for (int ni2 = 0; ni2 < 2; ++ni2) {
      float vmax = fmaxf(fmaxf(sm[0][ni2][0], sm[0][ni2][1]), fmaxf(sm[0][ni2][2], sm[0][ni2][3]));
#pragma unroll
      for (int mi = 1; mi < 4; ++mi)
        vmax = fmaxf(vmax, fmaxf(fmaxf(sm[mi][ni2][0], sm[mi][ni2][1]),
                                 fmaxf(sm[mi][ni2][2], sm[mi][ni2][3])));
      vmax = fmaxf(vmax, __shfl_xor(vmax, 16));
      vmax = fmaxf(vmax, __shfl_xor(vmax, 32));
      float nm = fmaxf(mrun[ni2], vmax);
      alpha[ni2] = exp2f(mrun[ni2] - nm);
      mrun[ni2] = nm;
    }
#pragma unroll
    for (int mi2 = 0; mi2 < 4; ++mi2)
#pragma unroll
      for (int ni2 = 0; ni2 < 2; ++ni2) {
        o[mi2][ni2][0] *= alpha[ni2]; o[mi2][ni2][1] *= alpha[ni2];
        o[mi2][ni2][2] *= alpha[ni2]; o[mi2][ni2][3] *= alpha[ni2];
      }
#pragma unroll
    for (int ni2 = 0; ni2 < 2; ++ni2) {
      o5[ni2][0] *= alpha[ni2]; o5[ni2][1] *= alpha[ni2];
      o5[ni2][2] *= alpha[ni2]; o5[ni2][3] *= alpha[ni2];
    }
    // p = exp2(s-m); pack straight into PV B-frags (tiles 2ks,2ks+1 -> one frag)
    bf16x8 pb[2][2];   // [ni2][ks]
#pragma unroll
    for (int ks = 0; ks < 2; ++ks)
#pragma unroll
      for (int ni2 = 0; ni2 < 2; ++ni2) {
        union { bf16x8 v; unsigned int u[4]; } pk;
        pk.u[0] = f2bf2(exp2f(sm[2 * ks][ni2][0] - mrun[ni2]), exp2f(sm[2 * ks][ni2][1] - mrun[ni2]));
        pk.u[1] = f2bf2(exp2f(sm[2 * ks][ni2][2] - mrun[ni2]), exp2f(sm[2 * ks][ni2][3] - mrun[ni2]));
        pk.u[2] = f2bf2(exp2f(sm[2 * ks + 1][ni2][0] - mrun[ni2]), exp2f(sm[2 * ks + 1][ni2][1] - mrun[ni2]));
        pk.u[3] = f2bf2(exp2f(sm[2 * ks + 1][ni2][2] - mrun[ni2]), exp2f(sm[2 * ks + 1][ni2][3] - mrun[ni2]));
        pb[ni2][ks] = pk.v;
      }
    // prefetch next tile (issued before PV so latency hides under MFMA)
    if (k0 + 64 < kend) {
#pragma unroll
      for (int i = 0; i < 4; ++i) {
        kpre[i] = *(const uint4*)(Khead + (size_t)(k0 + 64) * 64 + i * 1024 + p * 8);
        vpre[i] = *(const uint4*)(Vhead + (size_t)vgrow[i] * 2048 + (k0 + 64) + (p & 7) * 8);
      }
    }
    // O^T += V^T·P ; l += ones·P
#pragma unroll
    for (int ks = 0; ks < 2; ++ks) {
#pragma unroll
      for (int mi2 = 0; mi2 < 4; ++mi2) {
        int row = mi2 * 16 + ln;
        bf16x8 vf = *(const bf16x8*)(Vs + row * 64 + (((ks * 4 + quad) ^ (ln & 7)) << 3));
#pragma unroll
        for (int ni2 = 0; ni2 < 2; ++ni2)
          o[mi2][ni2] = __builtin_amdgcn_mfma_f32_16x16x32_bf16(vf, pb[ni2][ks], o[mi2][ni2], 0, 0, 0);
      }
#pragma unroll
      for (int ni2 = 0; ni2 < 2; ++ni2)
        o5[ni2] = __builtin_amdgcn_mfma_f32_16x16x32_bf16(ones, pb[ni2][ks], o5[ni2], 0, 0, 0);
    }
  }

  // ---- split-K merge: ki=0 waves -> LDS scratch, ki=1 waves combine+store ----
  __syncthreads();                     // all staging-buffer reads done
  float* scr = (float*)smem;           // 2 waves x 64 lanes x 40 floats = 20 KB
  const int base = (qi * 64 + lane) * 40;
  if (ki == 0) {
#pragma unroll
    for (int mi2 = 0; mi2 < 4; ++mi2)
#pragma unroll
      for (int ni2 = 0; ni2 < 2; ++ni2)
        *(floatx4*)(scr + base + (mi2 * 2 + ni2) * 4) = o[mi2][ni2];
    scr[base + 32] = mrun[0];
    scr[base + 33] = mrun[1];
    scr[base + 34] = o5[0][0];
    scr[base + 35] = o5[1][0];
  }
  __syncthreads();
  if (ki == 1) {
#pragma unroll
    for (int ni2 = 0; ni2 < 2; ++ni2) {
      float m0s = scr[base + 32 + ni2];
      float l0s = scr[base + 34 + ni2];
      float M = fmaxf(m0s, mrun[ni2]);
      float c0 = exp2f(m0s - M);
      float c1 = exp2f(mrun[ni2] - M);
      float inv = 1.f / (l0s * c0 + o5[ni2][0] * c1);
      float ic0 = c0 * inv, ic1 = c1 * inv;
      int t = q0 + ni2 * 16 + ln;
      size_t obase = ((size_t)b * 2048 + t) * 512 + h * 64;
#pragma unroll
      for (int mi2 = 0; mi2 < 4; ++mi2) {
        floatx4 p0 = *(const floatx4*)(scr + base + (mi2 * 2 + ni2) * 4);
        unsigned int u0 = f2bf2(p0[0] * ic0 + o[mi2][ni2][0] * ic1,
                                p0[1] * ic0 + o[mi2][ni2][1] * ic1);
        unsigned int u1 = f2bf2(p0[2] * ic0 + o[mi2][ni2][2] * ic1,
                                p0[3] * ic0 + o[mi2][ni2][3] * ic1);
        *(uint2*)(attnb + obase + mi2 * 16 + quad * 4) = make_uint2(u0, u1);
      }
    }
  }
}

// ---------------------------------------------------------------------------
// proj GEMM (swapped operands), unchanged
// ---------------------------------------------------------------------------
__global__ __launch_bounds__(256) void proj_kernel(
    const unsigned short* __restrict__ ab, const unsigned short* __restrict__ wpb,
    const float* __restrict__ proj_b, float* __restrict__ out) {
  __shared__ __align__(16) unsigned short As[128 * 32];
  __shared__ __align__(16) unsigned short Bs[128 * 32];
  const int tid = threadIdx.x;
  const int wave = tid >> 6, lane = tid & 63, ln = lane & 15, quad = lane >> 4;
  const int m0 = blockIdx.x * 128, n0 = blockIdx.y * 128;
  const int wr = (wave >> 1) * 64, wc = (wave & 1) * 64;

  floatx4 acc[4][4];
#pragma unroll
  for (int i = 0; i < 4; ++i)
#pragma unroll
    for (int j = 0; j < 4; ++j) acc[i][j] = (floatx4){0.f, 0.f, 0.f, 0.f};

  const int c0 = tid, c1 = tid + 256;
  const int ar0 = c0 >> 2, ak0 = (c0 & 3) * 8;
  const int ar1 = c1 >> 2, ak1 = (c1 & 3) * 8;

  for (int k0 = 0; k0 < 512; k0 += 32) {
    __syncthreads();
    gld_lds16(As + c0 * 8, ab + (size_t)(m0 + ar0) * 512 + k0 + ak0);
    gld_lds16(As + c1 * 8, ab + (size_t)(m0 + ar1) * 512 + k0 + ak1);
    gld_lds16(Bs + c0 * 8, wpb + (size_t)(n0 + ar0) * 512 + k0 + ak0);
    gld_lds16(Bs + c1 * 8, wpb + (size_t)(n0 + ar1) * 512 + k0 + ak1);
    __syncthreads();
    bf16x8 af[4], bfb[4];
#pragma unroll
    for (int mi = 0; mi < 4; ++mi)
      af[mi] = *(const bf16x8*)(As + (wr + mi * 16 + ln) * 32 + quad * 8);
#pragma unroll
    for (int ni = 0; ni < 4; ++ni)
      bfb[ni] = *(const bf16x8*)(Bs + (wc + ni * 16 + ln) * 32 + quad * 8);
#pragma unroll
    for (int mi = 0; mi < 4; ++mi)
#pragma unroll
      for (int ni = 0; ni < 4; ++ni)
        acc[mi][ni] = __builtin_amdgcn_mfma_f32_16x16x32_bf16(bfb[mi], af[ni], acc[mi][ni], 0, 0, 0);
  }

  float4 bias4[4];
#pragma unroll
  for (int mi = 0; mi < 4; ++mi)
    bias4[mi] = *(const float4*)(proj_b + n0 + wc + mi * 16 + quad * 4);
#pragma unroll
  for (int ni = 0; ni < 4; ++ni) {
    int t = m0 + wr + ni * 16 + ln;
#pragma unroll
    for (int mi = 0; mi < 4; ++mi) {
      int col = n0 + wc + mi * 16 + quad * 4;
      float4 st;
      st.x = acc[mi][ni][0] + bias4[mi].x;
      st.y = acc[mi][ni][1] + bias4[mi].y;
      st.z = acc[mi][ni][2] + bias4[mi].z;
      st.w = acc[mi][ni][3] + bias4[mi].w;
      *(float4*)(out + (size_t)t * 512 + col) = st;
    }
  }
}

// ---------------------------------------------------------------------------
extern "C" void kernel_launch(void* const* d_in, const int* in_sizes, int n_in,
                              void* d_out, int out_size, void* d_ws, size_t ws_size,
                              hipStream_t stream) {
  const float* x      = (const float*)d_in[0];
  const float* mask   = (const float*)d_in[1];
  const float* qkv_w  = (const float*)d_in[2];
  const float* qkv_b  = (const float*)d_in[3];
  const float* proj_w = (const float*)d_in[4];
  const float* proj_b = (const float*)d_in[5];
  float* out = (float*)d_out;

  char* ws = (char*)d_ws;
  unsigned short* xb   = (unsigned short*)(ws);
  unsigned short* wqb  = (unsigned short*)(ws + 8388608);
  unsigned short* wpb  = (unsigned short*)(ws + 9961472);
  float* cosT          = (float*)(ws + 10485760);
  float* sinT          = (float*)(ws + 10747904);
  unsigned short* Qb   = (unsigned short*)(ws + 11010048);
  unsigned short* Kb   = (unsigned short*)(ws + 19398656);
  unsigned short* Vtb  = (unsigned short*)(ws + 27787264);
  unsigned short* attnb= (unsigned short*)(ws + 36175872);

  prep_kernel<<<20736, 256, 0, stream>>>(x, qkv_w, proj_w, xb, wqb, wpb, cosT, sinT);
  dim3 g1(64, 12);
  qkv_kernel<<<g1, 256, 0, stream>>>(xb, wqb, qkv_b, cosT, sinT, Qb, Kb, Vtb);
  dim3 g2(32, 32);
  attn_kernel<<<g2, 256, 0, stream>>>(Qb, Kb, Vtb, mask, attnb);
  dim3 g3(64, 4);
  proj_kernel<<<g3, 256, 0, stream>>>(attnb, wpb, proj_b, out);
}

// Round 6
// 313.291 us; speedup vs baseline: 1.0285x; 1.0068x over previous
//
#include <hip/hip_runtime.h>
#include <math.h>

// ---------------------------------------------------------------------------
// HROMAttention: x(4,2048,512) -> QKV(+bias) -> RoPE -> MHA(8 heads, d=64)
//                -> proj(+bias). bf16 MFMA 16x16x32, fp32 accum.
// Round 6 = Round 4/5 structure with the REAL spill fix: attn uses plain
// __launch_bounds__(256) — no waves-per-EU minimum. Evidence: any explicit
// second arg pinned VGPR to 64/80 and spilled ~430-540 MB of scratch
// (WRITE_SIZE counter); R2's plain (256) allocated to the live set with zero
// spill. Expected: ~160 VGPR, 3 waves/SIMD, WRITE_SIZE ~16 MB.
// attn structure (verified correct in R4/R5):
//  - K-row permutation sigma at staging so S^T's C-regs pack directly into
//    PV B-frags (P never touches LDS)
//  - in-block 2-way split-K (4 waves = qsplit2 x ksplit2, 64q blocks) + merge
//  - XOR-swizzled unpadded LDS (32 KB), mask folded into MFMA C-init,
//    ones-MFMA row-sum l, exp2-domain softmax, pk_bf16 packing,
//    register prefetch of K/V staging loads
// ---------------------------------------------------------------------------

typedef __attribute__((ext_vector_type(8))) short bf16x8;
typedef __attribute__((ext_vector_type(4))) float floatx4;

#define LOG2E 1.44269504088896f

__device__ __forceinline__ unsigned short f2bf(float f) {
  unsigned int u = __float_as_uint(f);
  u += 0x7fffu + ((u >> 16) & 1u);   // round-to-nearest-even
  return (unsigned short)(u >> 16);
}

#if defined(__has_builtin)
#if __has_builtin(__builtin_amdgcn_cvt_pk_bf16_f32)
#define HAVE_PK_BF16 1
#endif
#endif

__device__ __forceinline__ unsigned int f2bf2(float a, float b) {
#ifdef HAVE_PK_BF16
  auto v = __builtin_amdgcn_cvt_pk_bf16_f32(a, b);
  union { decltype(v) x; unsigned int u; } c;
  c.x = v;
  return c.u;
#else
  return (unsigned int)f2bf(a) | ((unsigned int)f2bf(b) << 16);
#endif
}

__device__ __forceinline__ void gld_lds16(unsigned short* lds, const unsigned short* g) {
  __builtin_amdgcn_global_load_lds(
      (const __attribute__((address_space(1))) unsigned int*)g,
      (__attribute__((address_space(3))) unsigned int*)lds, 16, 0, 0);
}

// ---------------------------------------------------------------------------
// prep: bf16 conversions + RoPE cos/sin table (fp64 trig for accuracy)
// ---------------------------------------------------------------------------
__global__ __launch_bounds__(256) void prep_kernel(
    const float* __restrict__ x, const float* __restrict__ wq, const float* __restrict__ wp,
    unsigned short* __restrict__ xb, unsigned short* __restrict__ wqb,
    unsigned short* __restrict__ wpb, float* __restrict__ cosT, float* __restrict__ sinT) {
  int i = blockIdx.x * 256 + threadIdx.x;
  if (i < 4194304) {
    xb[i] = f2bf(x[i]);
  } else if (i < 4980736) {
    int j = i - 4194304; wqb[j] = f2bf(wq[j]);
  } else if (i < 5242880) {
    int j = i - 4980736; wpb[j] = f2bf(wp[j]);
  } else if (i < 5308416) {
    int j = i - 5242880;
    int t = j >> 5, f = j & 31;
    double fr = (double)t * pow(10000.0, -(double)f / 32.0);
    cosT[j] = (float)cos(fr);
    sinT[j] = (float)sin(fr);
  }
}

// ---------------------------------------------------------------------------
// QKV GEMM: 128x128 tile, BK=32, 4 waves each 64x64. (unchanged)
// ---------------------------------------------------------------------------
__global__ __launch_bounds__(256) void qkv_kernel(
    const unsigned short* __restrict__ xb, const unsigned short* __restrict__ wqb,
    const float* __restrict__ qkv_b, const float* __restrict__ cosT,
    const float* __restrict__ sinT, unsigned short* __restrict__ Qb,
    unsigned short* __restrict__ Kb, unsigned short* __restrict__ Vtb) {
  __shared__ __align__(16) unsigned short As[128 * 32];
  __shared__ __align__(16) unsigned short Bs[128 * 32];
  const int tid = threadIdx.x;
  const int wave = tid >> 6, lane = tid & 63, ln = lane & 15, quad = lane >> 4;
  const int m0 = blockIdx.x * 128, n0 = blockIdx.y * 128;
  const int wr = (wave >> 1) * 64, wc = (wave & 1) * 64;
  const bool isV = (blockIdx.y >= 8);

  floatx4 acc[4][4];
#pragma unroll
  for (int i = 0; i < 4; ++i)
#pragma unroll
    for (int j = 0; j < 4; ++j) acc[i][j] = (floatx4){0.f, 0.f, 0.f, 0.f};

  const int c0 = tid, c1 = tid + 256;
  const int ar0 = c0 >> 2, ak0 = (c0 & 3) * 8;
  const int ar1 = c1 >> 2, ak1 = (c1 & 3) * 8;

  for (int k0 = 0; k0 < 512; k0 += 32) {
    __syncthreads();
    gld_lds16(As + c0 * 8, xb + (size_t)(m0 + ar0) * 512 + k0 + ak0);
    gld_lds16(As + c1 * 8, xb + (size_t)(m0 + ar1) * 512 + k0 + ak1);
    gld_lds16(Bs + c0 * 8, wqb + (size_t)(n0 + ar0) * 512 + k0 + ak0);
    gld_lds16(Bs + c1 * 8, wqb + (size_t)(n0 + ar1) * 512 + k0 + ak1);
    __syncthreads();
    bf16x8 af[4], bfb[4];
#pragma unroll
    for (int mi = 0; mi < 4; ++mi)
      af[mi] = *(const bf16x8*)(As + (wr + mi * 16 + ln) * 32 + quad * 8);
#pragma unroll
    for (int ni = 0; ni < 4; ++ni)
      bfb[ni] = *(const bf16x8*)(Bs + (wc + ni * 16 + ln) * 32 + quad * 8);
    if (isV) {
#pragma unroll
      for (int mi = 0; mi < 4; ++mi)
#pragma unroll
        for (int ni = 0; ni < 4; ++ni)
          acc[mi][ni] = __builtin_amdgcn_mfma_f32_16x16x32_bf16(af[mi], bfb[ni], acc[mi][ni], 0, 0, 0);
    } else {
#pragma unroll
      for (int mi = 0; mi < 4; ++mi)
#pragma unroll
        for (int ni = 0; ni < 4; ++ni)
          acc[mi][ni] = __builtin_amdgcn_mfma_f32_16x16x32_bf16(bfb[mi], af[ni], acc[mi][ni], 0, 0, 0);
    }
  }

  const int colbase = n0 + wc;
  const int mat = colbase >> 9;
  const int h = (colbase & 511) >> 6;

  if (isV) {
    float bias[4];
#pragma unroll
    for (int ni = 0; ni < 4; ++ni) bias[ni] = qkv_b[colbase + ni * 16 + ln];
#pragma unroll
    for (int mi = 0; mi < 4; ++mi) {
      int row0 = m0 + wr + mi * 16 + quad * 4;
      int bidx = row0 >> 11, t = row0 & 2047;
#pragma unroll
      for (int ni = 0; ni < 4; ++ni) {
        int d = ni * 16 + ln;
        unsigned int u0 = f2bf2(acc[mi][ni][0] + bias[ni], acc[mi][ni][1] + bias[ni]);
        unsigned int u1 = f2bf2(acc[mi][ni][2] + bias[ni], acc[mi][ni][3] + bias[ni]);
        *(uint2*)(Vtb + ((size_t)(bidx * 8 + h) * 64 + d) * 2048 + t) = make_uint2(u0, u1);
      }
    }
  } else {
    unsigned short* dst = (mat == 0) ? Qb : Kb;
    const float sc = (mat == 0) ? 0.125f * LOG2E : 1.0f;
    float4 blo[2], bhi[2];
#pragma unroll
    for (int mi = 0; mi < 2; ++mi) {
      blo[mi] = *(const float4*)(qkv_b + colbase + mi * 16 + quad * 4);
      bhi[mi] = *(const float4*)(qkv_b + colbase + 32 + mi * 16 + quad * 4);
    }
#pragma unroll
    for (int ni = 0; ni < 4; ++ni) {
      int row = m0 + wr + ni * 16 + ln;
      int bidx = row >> 11, t = row & 2047;
      unsigned short* tb = dst + ((size_t)(bidx * 8 + h) * 2048 + t) * 64;
#pragma unroll
      for (int mi = 0; mi < 2; ++mi) {
        int dbase = mi * 16 + quad * 4;
        float4 c4 = *(const float4*)(cosT + t * 32 + dbase);
        float4 s4 = *(const float4*)(sinT + t * 32 + dbase);
        float xl0 = acc[mi][ni][0] + blo[mi].x, xh0 = acc[mi + 2][ni][0] + bhi[mi].x;
        float xl1 = acc[mi][ni][1] + blo[mi].y, xh1 = acc[mi + 2][ni][1] + bhi[mi].y;
        float xl2 = acc[mi][ni][2] + blo[mi].z, xh2 = acc[mi + 2][ni][2] + bhi[mi].z;
        float xl3 = acc[mi][ni][3] + blo[mi].w, xh3 = acc[mi + 2][ni][3] + bhi[mi].w;
        unsigned int lo01 = f2bf2((xl0 * c4.x - xh0 * s4.x) * sc, (xl1 * c4.y - xh1 * s4.y) * sc);
        unsigned int lo23 = f2bf2((xl2 * c4.z - xh2 * s4.z) * sc, (xl3 * c4.w - xh3 * s4.w) * sc);
        unsigned int hi01 = f2bf2((xh0 * c4.x + xl0 * s4.x) * sc, (xh1 * c4.y + xl1 * s4.y) * sc);
        unsigned int hi23 = f2bf2((xh2 * c4.z + xl2 * s4.z) * sc, (xh3 * c4.w + xl3 * s4.w) * sc);
        *(uint2*)(tb + dbase) = make_uint2(lo01, lo23);
        *(uint2*)(tb + 32 + dbase) = make_uint2(hi01, hi23);
      }
    }
  }
}

// ---------------------------------------------------------------------------
// Flash attention R6 (= R4 logic, plain __launch_bounds__(256) — allocator
// sizes VGPRs to the live set, no scratch spill).
// Block 256 thr = 4 waves = (qsplit 2)x(ksplit 2); block covers 64 q; wave
// (qi,ki) does q0+qi*32, k in [ki*1024,(ki+1)*1024).
// K staged with row-permutation sigma so S^T C-regs pack directly into PV
// B-frags; P never touches LDS. XOR-swizzled unpadded LDS.
// ---------------------------------------------------------------------------
__global__ __launch_bounds__(256) void attn_kernel(
    const unsigned short* __restrict__ Qb, const unsigned short* __restrict__ Kb,
    const unsigned short* __restrict__ Vtb, const float* __restrict__ mask,
    unsigned short* __restrict__ attnb) {
  __shared__ __align__(16) unsigned short smem[16384];  // 32 KB

  const int tid = threadIdx.x;
  const int wave = tid >> 6, lane = tid & 63, ln = lane & 15, quad = lane >> 4;
  const int qi = wave & 1, ki = wave >> 1;
  const int bh = blockIdx.y, b = bh >> 3, h = bh & 7;
  const int q0 = blockIdx.x * 64 + qi * 32;
  const int kbeg = ki * 1024, kend = kbeg + 1024;

  const unsigned short* Qhead = Qb + (size_t)bh * 2048 * 64;
  const unsigned short* Khead = Kb + (size_t)bh * 2048 * 64;
  const unsigned short* Vhead = Vtb + (size_t)bh * 64 * 2048;
  unsigned short* Ks = smem + ki * 4096;
  unsigned short* Vs = smem + 8192 + ki * 4096;

  // ---- staging map (pair-local p in [0,128)): 4 passes x 16 B ----
  const int p = tid & 127;
  int offK[4], offV[4], vgrow[4];
#pragma unroll
  for (int i = 0; i < 4; ++i) {
    int g = i * 16 + (p >> 3);        // global row (K: t_k-local; V: d)
    int c = p & 7;                    // 16B chunk within row
    int s = (g & 0x23) | ((g & 4) << 2) | ((g & 16) >> 1) | ((g & 8) >> 1);  // sigma(g)
    offK[i] = s * 64 + ((c ^ (s & 7)) << 3);
    offV[i] = g * 64 + ((c ^ (g & 7)) << 3);
    vgrow[i] = g;
  }

  // Q B-frags (B[n=q][k=d]), loaded once
  bf16x8 qf[2][2];
#pragma unroll
  for (int ni2 = 0; ni2 < 2; ++ni2)
#pragma unroll
    for (int ks = 0; ks < 2; ++ks)
      qf[ni2][ks] = *(const bf16x8*)(Qhead + (size_t)(q0 + ni2 * 16 + ln) * 64 + ks * 32 + quad * 8);

  bf16x8 ones;
#pragma unroll
  for (int j = 0; j < 8; ++j) ones[j] = (short)0x3F80;

  floatx4 o[4][2];   // O^T: [d-tile][q-tile]
#pragma unroll
  for (int mi2 = 0; mi2 < 4; ++mi2)
#pragma unroll
    for (int ni2 = 0; ni2 < 2; ++ni2) o[mi2][ni2] = (floatx4){0.f, 0.f, 0.f, 0.f};
  floatx4 o5[2] = {(floatx4){0.f, 0.f, 0.f, 0.f}, (floatx4){0.f, 0.f, 0.f, 0.f}};
  float mrun[2] = {-INFINITY, -INFINITY};

  // initial prefetch
  uint4 kpre[4], vpre[4];
#pragma unroll
  for (int i = 0; i < 4; ++i) {
    kpre[i] = *(const uint4*)(Khead + (size_t)kbeg * 64 + i * 1024 + p * 8);
    vpre[i] = *(const uint4*)(Vhead + (size_t)vgrow[i] * 2048 + kbeg + (p & 7) * 8);
  }

  for (int k0 = kbeg; k0 < kend; k0 += 64) {
    __syncthreads();
#pragma unroll
    for (int i = 0; i < 4; ++i) {
      *(uint4*)(Ks + offK[i]) = kpre[i];
      *(uint4*)(Vs + offV[i]) = vpre[i];
    }
    __syncthreads();

    // mask -> C-init at permuted row addresses (t_k = 32*(mi>>1)+4*(mi&1)+8*quad+r)
    floatx4 cini[4];
#pragma unroll
    for (int mi = 0; mi < 4; ++mi) {
      float4 mv = *(const float4*)(mask + b * 2048 + k0 + 32 * (mi >> 1) + 4 * (mi & 1) + 8 * quad);
      cini[mi] = (floatx4){mv.x * LOG2E, mv.y * LOG2E, mv.z * LOG2E, mv.w * LOG2E};
    }
    // S^T = K·Q^T from swizzled LDS
    floatx4 sm[4][2];
#pragma unroll
    for (int mi = 0; mi < 4; ++mi) {
      int row = mi * 16 + ln;
      bf16x8 kf0 = *(const bf16x8*)(Ks + row * 64 + ((quad ^ (ln & 7)) << 3));
      bf16x8 kf1 = *(const bf16x8*)(Ks + row * 64 + (((4 + quad) ^ (ln & 7)) << 3));
#pragma unroll
      for (int ni2 = 0; ni2 < 2; ++ni2) {
        floatx4 a = cini[mi];
        a = __builtin_amdgcn_mfma_f32_16x16x32_bf16(kf0, qf[ni2][0], a, 0, 0, 0);
        a = __builtin_amdgcn_mfma_f32_16x16x32_bf16(kf1, qf[ni2][1], a, 0, 0, 0);
        sm[mi][ni2] = a;
      }
    }
    // online softmax (per lane one q-col; combine quads with 2 shuffles)
    float alpha[2];
#pragma unroll
    for (int ni2 = 0; ni2 < 2; ++ni2) {
      float vmax = fmaxf(fmaxf(sm[0][ni2][0], sm[0][ni2][1]), fmaxf(sm[0][ni2][2], sm[0][ni2][3]));
#pragma unroll
      for (int mi = 1; mi < 4; ++mi)
        vmax = fmaxf(vmax, fmaxf(fmaxf(sm[mi][ni2][0], sm[mi][ni2][1]),
                                 fmaxf(sm[mi][ni2][2], sm[mi][ni2][3])));
      vmax = fmaxf(vmax, __shfl_xor(vmax, 16));
      vmax = fmaxf(vmax, __shfl_xor(vmax, 32));
      float nm = fmaxf(mrun[ni2], vmax);
      alpha[ni2] = exp2f(mrun[ni2] - nm);
      mrun[ni2] = nm;
    }
#pragma unroll
    for (int mi2 = 0; mi2 < 4; ++mi2)
#pragma unroll
      for (int ni2 = 0; ni2 < 2; ++ni2) {
        o[mi2][ni2][0] *= alpha[ni2]; o[mi2][ni2][1] *= alpha[ni2];
        o[mi2][ni2][2] *= alpha[ni2]; o[mi2][ni2][3] *= alpha[ni2];
      }
#pragma unroll
    for (int ni2 = 0; ni2 < 2; ++ni2) {
      o5[ni2][0] *= alpha[ni2]; o5[ni2][1] *= alpha[ni2];
      o5[ni2][2] *= alpha[ni2]; o5[ni2][3] *= alpha[ni2];
    }
    // p = exp2(s-m); pack straight into PV B-frags (tiles 2ks,2ks+1 -> one frag)
    bf16x8 pb[2][2];   // [ni2][ks]
#pragma unroll
    for (int ks = 0; ks < 2; ++ks)
#pragma unroll
      for (int ni2 = 0; ni2 < 2; ++ni2) {
        union { bf16x8 v; unsigned int u[4]; } pk;
        pk.u[0] = f2bf2(exp2f(sm[2 * ks][ni2][0] - mrun[ni2]), exp2f(sm[2 * ks][ni2][1] - mrun[ni2]));
        pk.u[1] = f2bf2(exp2f(sm[2 * ks][ni2][2] - mrun[ni2]), exp2f(sm[2 * ks][ni2][3] - mrun[ni2]));
        pk.u[2] = f2bf2(exp2f(sm[2 * ks + 1][ni2][0] - mrun[ni2]), exp2f(sm[2 * ks + 1][ni2][1] - mrun[ni2]));
        pk.u[3] = f2bf2(exp2f(sm[2 * ks + 1][ni2][2] - mrun[ni2]), exp2f(sm[2 * ks + 1][ni2][3] - mrun[ni2]));
        pb[ni2][ks] = pk.v;
      }
    // prefetch next tile (issued before PV so latency hides under MFMA)
    if (k0 + 64 < kend) {
#pragma unroll
      for (int i = 0; i < 4; ++i) {
        kpre[i] = *(const uint4*)(Khead + (size_t)(k0 + 64) * 64 + i * 1024 + p * 8);
        vpre[i] = *(const uint4*)(Vhead + (size_t)vgrow[i] * 2048 + (k0 + 64) + (p & 7) * 8);
      }
    }
    // O^T += V^T·P ; l += ones·P
#pragma unroll
    for (int ks = 0; ks < 2; ++ks) {
#pragma unroll
      for (int mi2 = 0; mi2 < 4; ++mi2) {
        int row = mi2 * 16 + ln;
        bf16x8 vf = *(const bf16x8*)(Vs + row * 64 + (((ks * 4 + quad) ^ (ln & 7)) << 3));
#pragma unroll
        for (int ni2 = 0; ni2 < 2; ++ni2)
          o[mi2][ni2] = __builtin_amdgcn_mfma_f32_16x16x32_bf16(vf, pb[ni2][ks], o[mi2][ni2], 0, 0, 0);
      }
#pragma unroll
      for (int ni2 = 0; ni2 < 2; ++ni2)
        o5[ni2] = __builtin_amdgcn_mfma_f32_16x16x32_bf16(ones, pb[ni2][ks], o5[ni2], 0, 0, 0);
    }
  }

  // ---- split-K merge: ki=0 waves -> LDS scratch, ki=1 waves combine+store ----
  __syncthreads();                     // all staging-buffer reads done
  float* scr = (float*)smem;           // 2 waves x 64 lanes x 40 floats = 20 KB
  const int base = (qi * 64 + lane) * 40;
  if (ki == 0) {
#pragma unroll
    for (int mi2 = 0; mi2 < 4; ++mi2)
#pragma unroll
      for (int ni2 = 0; ni2 < 2; ++ni2)
        *(floatx4*)(scr + base + (mi2 * 2 + ni2) * 4) = o[mi2][ni2];
    scr[base + 32] = mrun[0];
    scr[base + 33] = mrun[1];
    scr[base + 34] = o5[0][0];
    scr[base + 35] = o5[1][0];
  }
  __syncthreads();
  if (ki == 1) {
#pragma unroll
    for (int ni2 = 0; ni2 < 2; ++ni2) {
      float m0s = scr[base + 32 + ni2];
      float l0s = scr[base + 34 + ni2];
      float M = fmaxf(m0s, mrun[ni2]);
      float c0 = exp2f(m0s - M);
      float c1 = exp2f(mrun[ni2] - M);
      float inv = 1.f / (l0s * c0 + o5[ni2][0] * c1);
      float ic0 = c0 * inv, ic1 = c1 * inv;
      int t = q0 + ni2 * 16 + ln;
      size_t obase = ((size_t)b * 2048 + t) * 512 + h * 64;
#pragma unroll
      for (int mi2 = 0; mi2 < 4; ++mi2) {
        floatx4 p0 = *(const floatx4*)(scr + base + (mi2 * 2 + ni2) * 4);
        unsigned int u0 = f2bf2(p0[0] * ic0 + o[mi2][ni2][0] * ic1,
                                p0[1] * ic0 + o[mi2][ni2][1] * ic1);
        unsigned int u1 = f2bf2(p0[2] * ic0 + o[mi2][ni2][2] * ic1,
                                p0[3] * ic0 + o[mi2][ni2][3] * ic1);
        *(uint2*)(attnb + obase + mi2 * 16 + quad * 4) = make_uint2(u0, u1);
      }
    }
  }
}

// ---------------------------------------------------------------------------
// proj GEMM (swapped operands), unchanged
// ---------------------------------------------------------------------------
__global__ __launch_bounds__(256) void proj_kernel(
    const unsigned short* __restrict__ ab, const unsigned short* __restrict__ wpb,
    const float* __restrict__ proj_b, float* __restrict__ out) {
  __shared__ __align__(16) unsigned short As[128 * 32];
  __shared__ __align__(16) unsigned short Bs[128 * 32];
  const int tid = threadIdx.x;
  const int wave = tid >> 6, lane = tid & 63, ln = lane & 15, quad = lane >> 4;
  const int m0 = blockIdx.x * 128, n0 = blockIdx.y * 128;
  const int wr = (wave >> 1) * 64, wc = (wave & 1) * 64;

  floatx4 acc[4][4];
#pragma unroll
  for (int i = 0; i < 4; ++i)
#pragma unroll
    for (int j = 0; j < 4; ++j) acc[i][j] = (floatx4){0.f, 0.f, 0.f, 0.f};

  const int c0 = tid, c1 = tid + 256;
  const int ar0 = c0 >> 2, ak0 = (c0 & 3) * 8;
  const int ar1 = c1 >> 2, ak1 = (c1 & 3) * 8;

  for (int k0 = 0; k0 < 512; k0 += 32) {
    __syncthreads();
    gld_lds16(As + c0 * 8, ab + (size_t)(m0 + ar0) * 512 + k0 + ak0);
    gld_lds16(As + c1 * 8, ab + (size_t)(m0 + ar1) * 512 + k0 + ak1);
    gld_lds16(Bs + c0 * 8, wpb + (size_t)(n0 + ar0) * 512 + k0 + ak0);
    gld_lds16(Bs + c1 * 8, wpb + (size_t)(n0 + ar1) * 512 + k0 + ak1);
    __syncthreads();
    bf16x8 af[4], bfb[4];
#pragma unroll
    for (int mi = 0; mi < 4; ++mi)
      af[mi] = *(const bf16x8*)(As + (wr + mi * 16 + ln) * 32 + quad * 8);
#pragma unroll
    for (int ni = 0; ni < 4; ++ni)
      bfb[ni] = *(const bf16x8*)(Bs + (wc + ni * 16 + ln) * 32 + quad * 8);
#pragma unroll
    for (int mi = 0; mi < 4; ++mi)
#pragma unroll
      for (int ni = 0; ni < 4; ++ni)
        acc[mi][ni] = __builtin_amdgcn_mfma_f32_16x16x32_bf16(bfb[mi], af[ni], acc[mi][ni], 0, 0, 0);
  }

  float4 bias4[4];
#pragma unroll
  for (int mi = 0; mi < 4; ++mi)
    bias4[mi] = *(const float4*)(proj_b + n0 + wc + mi * 16 + quad * 4);
#pragma unroll
  for (int ni = 0; ni < 4; ++ni) {
    int t = m0 + wr + ni * 16 + ln;
#pragma unroll
    for (int mi = 0; mi < 4; ++mi) {
      int col = n0 + wc + mi * 16 + quad * 4;
      float4 st;
      st.x = acc[mi][ni][0] + bias4[mi].x;
      st.y = acc[mi][ni][1] + bias4[mi].y;
      st.z = acc[mi][ni][2] + bias4[mi].z;
      st.w = acc[mi][ni][3] + bias4[mi].w;
      *(float4*)(out + (size_t)t * 512 + col) = st;
    }
  }
}

// ---------------------------------------------------------------------------
extern "C" void kernel_launch(void* const* d_in, const int* in_sizes, int n_in,
                              void* d_out, int out_size, void* d_ws, size_t ws_size,
                              hipStream_t stream) {
  const float* x      = (const float*)d_in[0];
  const float* mask   = (const float*)d_in[1];
  const float* qkv_w  = (const float*)d_in[2];
  const float* qkv_b  = (const float*)d_in[3];
  const float* proj_w = (const float*)d_in[4];
  const float* proj_b = (const float*)d_in[5];
  float* out = (float*)d_out;

  char* ws = (char*)d_ws;
  unsigned short* xb   = (unsigned short*)(ws);
  unsigned short* wqb  = (unsigned short*)(ws + 8388608);
  unsigned short* wpb  = (unsigned short*)(ws + 9961472);
  float* cosT          = (float*)(ws + 10485760);
  float* sinT          = (float*)(ws + 10747904);
  unsigned short* Qb   = (unsigned short*)(ws + 11010048);
  unsigned short* Kb   = (unsigned short*)(ws + 19398656);
  unsigned short* Vtb  = (unsigned short*)(ws + 27787264);
  unsigned short* attnb= (unsigned short*)(ws + 36175872);

  prep_kernel<<<20736, 256, 0, stream>>>(x, qkv_w, proj_w, xb, wqb, wpb, cosT, sinT);
  dim3 g1(64, 12);
  qkv_kernel<<<g1, 256, 0, stream>>>(xb, wqb, qkv_b, cosT, sinT, Qb, Kb, Vtb);
  dim3 g2(32, 32);
  attn_kernel<<<g2, 256, 0, stream>>>(Qb, Kb, Vtb, mask, attnb);
  dim3 g3(64, 4);
  proj_kernel<<<g3, 256, 0, stream>>>(attnb, wpb, proj_b, out);
}

// Round 7
// 245.271 us; speedup vs baseline: 1.3137x; 1.2773x over previous
//
#include <hip/hip_runtime.h>
#include <math.h>

// ---------------------------------------------------------------------------
// HROMAttention: x(4,2048,512) -> QKV(+bias) -> RoPE -> MHA(8 heads, d=64)
//                -> proj(+bias). bf16 MFMA 16x16x32, fp32 accum.
// Round 7 attn: kill the register-pressure spill STRUCTURALLY.
// R4-R6 register-staged K/V prefetch (kpre/vpre = 32 VGPRs) made the live set
// ~160 regs; the allocator pinned 64/80/112 and spilled 340-540 MB of scratch
// (WRITE_SIZE counter) at every launch-bounds setting. R7 stages K/V with
// __builtin_amdgcn_global_load_lds (async DMA, no VGPR round-trip, m97
// pattern). The sigma row-permutation + XOR bank-swizzle move to the SOURCE
// side (per-lane gptr), since the LDS dest is wave-uniform+lane*16; LDS
// content is bit-identical to R4's verified layout, consume code untouched.
// qi=0 wave DMAs K, qi=1 wave DMAs V (R6 duplicated both per wave).
// ---------------------------------------------------------------------------

typedef __attribute__((ext_vector_type(8))) short bf16x8;
typedef __attribute__((ext_vector_type(4))) float floatx4;

#define LOG2E 1.44269504088896f

__device__ __forceinline__ unsigned short f2bf(float f) {
  unsigned int u = __float_as_uint(f);
  u += 0x7fffu + ((u >> 16) & 1u);   // round-to-nearest-even
  return (unsigned short)(u >> 16);
}

#if defined(__has_builtin)
#if __has_builtin(__builtin_amdgcn_cvt_pk_bf16_f32)
#define HAVE_PK_BF16 1
#endif
#endif

__device__ __forceinline__ unsigned int f2bf2(float a, float b) {
#ifdef HAVE_PK_BF16
  auto v = __builtin_amdgcn_cvt_pk_bf16_f32(a, b);
  union { decltype(v) x; unsigned int u; } c;
  c.x = v;
  return c.u;
#else
  return (unsigned int)f2bf(a) | ((unsigned int)f2bf(b) << 16);
#endif
}

__device__ __forceinline__ void gld_lds16(unsigned short* lds, const unsigned short* g) {
  __builtin_amdgcn_global_load_lds(
      (const __attribute__((address_space(1))) unsigned int*)g,
      (__attribute__((address_space(3))) unsigned int*)lds, 16, 0, 0);
}

// ---------------------------------------------------------------------------
// prep: bf16 conversions + RoPE cos/sin table (fp64 trig for accuracy)
// ---------------------------------------------------------------------------
__global__ __launch_bounds__(256) void prep_kernel(
    const float* __restrict__ x, const float* __restrict__ wq, const float* __restrict__ wp,
    unsigned short* __restrict__ xb, unsigned short* __restrict__ wqb,
    unsigned short* __restrict__ wpb, float* __restrict__ cosT, float* __restrict__ sinT) {
  int i = blockIdx.x * 256 + threadIdx.x;
  if (i < 4194304) {
    xb[i] = f2bf(x[i]);
  } else if (i < 4980736) {
    int j = i - 4194304; wqb[j] = f2bf(wq[j]);
  } else if (i < 5242880) {
    int j = i - 4980736; wpb[j] = f2bf(wp[j]);
  } else if (i < 5308416) {
    int j = i - 5242880;
    int t = j >> 5, f = j & 31;
    double fr = (double)t * pow(10000.0, -(double)f / 32.0);
    cosT[j] = (float)cos(fr);
    sinT[j] = (float)sin(fr);
  }
}

// ---------------------------------------------------------------------------
// QKV GEMM: 128x128 tile, BK=32, 4 waves each 64x64. (unchanged)
// ---------------------------------------------------------------------------
__global__ __launch_bounds__(256) void qkv_kernel(
    const unsigned short* __restrict__ xb, const unsigned short* __restrict__ wqb,
    const float* __restrict__ qkv_b, const float* __restrict__ cosT,
    const float* __restrict__ sinT, unsigned short* __restrict__ Qb,
    unsigned short* __restrict__ Kb, unsigned short* __restrict__ Vtb) {
  __shared__ __align__(16) unsigned short As[128 * 32];
  __shared__ __align__(16) unsigned short Bs[128 * 32];
  const int tid = threadIdx.x;
  const int wave = tid >> 6, lane = tid & 63, ln = lane & 15, quad = lane >> 4;
  const int m0 = blockIdx.x * 128, n0 = blockIdx.y * 128;
  const int wr = (wave >> 1) * 64, wc = (wave & 1) * 64;
  const bool isV = (blockIdx.y >= 8);

  floatx4 acc[4][4];
#pragma unroll
  for (int i = 0; i < 4; ++i)
#pragma unroll
    for (int j = 0; j < 4; ++j) acc[i][j] = (floatx4){0.f, 0.f, 0.f, 0.f};

  const int c0 = tid, c1 = tid + 256;
  const int ar0 = c0 >> 2, ak0 = (c0 & 3) * 8;
  const int ar1 = c1 >> 2, ak1 = (c1 & 3) * 8;

  for (int k0 = 0; k0 < 512; k0 += 32) {
    __syncthreads();
    gld_lds16(As + c0 * 8, xb + (size_t)(m0 + ar0) * 512 + k0 + ak0);
    gld_lds16(As + c1 * 8, xb + (size_t)(m0 + ar1) * 512 + k0 + ak1);
    gld_lds16(Bs + c0 * 8, wqb + (size_t)(n0 + ar0) * 512 + k0 + ak0);
    gld_lds16(Bs + c1 * 8, wqb + (size_t)(n0 + ar1) * 512 + k0 + ak1);
    __syncthreads();
    bf16x8 af[4], bfb[4];
#pragma unroll
    for (int mi = 0; mi < 4; ++mi)
      af[mi] = *(const bf16x8*)(As + (wr + mi * 16 + ln) * 32 + quad * 8);
#pragma unroll
    for (int ni = 0; ni < 4; ++ni)
      bfb[ni] = *(const bf16x8*)(Bs + (wc + ni * 16 + ln) * 32 + quad * 8);
    if (isV) {
#pragma unroll
      for (int mi = 0; mi < 4; ++mi)
#pragma unroll
        for (int ni = 0; ni < 4; ++ni)
          acc[mi][ni] = __builtin_amdgcn_mfma_f32_16x16x32_bf16(af[mi], bfb[ni], acc[mi][ni], 0, 0, 0);
    } else {
#pragma unroll
      for (int mi = 0; mi < 4; ++mi)
#pragma unroll
        for (int ni = 0; ni < 4; ++ni)
          acc[mi][ni] = __builtin_amdgcn_mfma_f32_16x16x32_bf16(bfb[mi], af[ni], acc[mi][ni], 0, 0, 0);
    }
  }

  const int colbase = n0 + wc;
  const int mat = colbase >> 9;
  const int h = (colbase & 511) >> 6;

  if (isV) {
    float bias[4];
#pragma unroll
    for (int ni = 0; ni < 4; ++ni) bias[ni] = qkv_b[colbase + ni * 16 + ln];
#pragma unroll
    for (int mi = 0; mi < 4; ++mi) {
      int row0 = m0 + wr + mi * 16 + quad * 4;
      int bidx = row0 >> 11, t = row0 & 2047;
#pragma unroll
      for (int ni = 0; ni < 4; ++ni) {
        int d = ni * 16 + ln;
        unsigned int u0 = f2bf2(acc[mi][ni][0] + bias[ni], acc[mi][ni][1] + bias[ni]);
        unsigned int u1 = f2bf2(acc[mi][ni][2] + bias[ni], acc[mi][ni][3] + bias[ni]);
        *(uint2*)(Vtb + ((size_t)(bidx * 8 + h) * 64 + d) * 2048 + t) = make_uint2(u0, u1);
      }
    }
  } else {
    unsigned short* dst = (mat == 0) ? Qb : Kb;
    const float sc = (mat == 0) ? 0.125f * LOG2E : 1.0f;
    float4 blo[2], bhi[2];
#pragma unroll
    for (int mi = 0; mi < 2; ++mi) {
      blo[mi] = *(const float4*)(qkv_b + colbase + mi * 16 + quad * 4);
      bhi[mi] = *(const float4*)(qkv_b + colbase + 32 + mi * 16 + quad * 4);
    }
#pragma unroll
    for (int ni = 0; ni < 4; ++ni) {
      int row = m0 + wr + ni * 16 + ln;
      int bidx = row >> 11, t = row & 2047;
      unsigned short* tb = dst + ((size_t)(bidx * 8 + h) * 2048 + t) * 64;
#pragma unroll
      for (int mi = 0; mi < 2; ++mi) {
        int dbase = mi * 16 + quad * 4;
        float4 c4 = *(const float4*)(cosT + t * 32 + dbase);
        float4 s4 = *(const float4*)(sinT + t * 32 + dbase);
        float xl0 = acc[mi][ni][0] + blo[mi].x, xh0 = acc[mi + 2][ni][0] + bhi[mi].x;
        float xl1 = acc[mi][ni][1] + blo[mi].y, xh1 = acc[mi + 2][ni][1] + bhi[mi].y;
        float xl2 = acc[mi][ni][2] + blo[mi].z, xh2 = acc[mi + 2][ni][2] + bhi[mi].z;
        float xl3 = acc[mi][ni][3] + blo[mi].w, xh3 = acc[mi + 2][ni][3] + bhi[mi].w;
        unsigned int lo01 = f2bf2((xl0 * c4.x - xh0 * s4.x) * sc, (xl1 * c4.y - xh1 * s4.y) * sc);
        unsigned int lo23 = f2bf2((xl2 * c4.z - xh2 * s4.z) * sc, (xl3 * c4.w - xh3 * s4.w) * sc);
        unsigned int hi01 = f2bf2((xh0 * c4.x + xl0 * s4.x) * sc, (xh1 * c4.y + xl1 * s4.y) * sc);
        unsigned int hi23 = f2bf2((xh2 * c4.z + xl2 * s4.z) * sc, (xh3 * c4.w + xl3 * s4.w) * sc);
        *(uint2*)(tb + dbase) = make_uint2(lo01, lo23);
        *(uint2*)(tb + 32 + dbase) = make_uint2(hi01, hi23);
      }
    }
  }
}

// ---------------------------------------------------------------------------
// Flash attention R7. Block 256 = 4 waves = (qsplit 2)x(ksplit 2); 64 q/block;
// wave(qi,ki) computes q0+qi*32, k in [ki*1024,(ki+1)*1024).
// K/V staged by global_load_lds DMA (no VGPR staging, no ds_write):
//   qi=0 wave issues the ki-stream's 8 K DMAs, qi=1 wave the 8 V DMAs.
//   sigma row-perm + XOR swizzle applied on the SOURCE address per lane; LDS
//   content identical to R4's verified layout. m97 2-barrier K-loop drains
//   the DMA queue at the second __syncthreads.
// S^T C-regs pack directly into PV B-frags (P never touches LDS); mask in
// MFMA C-init; ones-MFMA row-sum l; exp2 softmax; split-K LDS merge.
// ---------------------------------------------------------------------------
__global__ __launch_bounds__(256) void attn_kernel(
    const unsigned short* __restrict__ Qb, const unsigned short* __restrict__ Kb,
    const unsigned short* __restrict__ Vtb, const float* __restrict__ mask,
    unsigned short* __restrict__ attnb) {
  __shared__ __align__(16) unsigned short smem[16384];  // 32 KB

  const int tid = threadIdx.x;
  const int wave = tid >> 6, lane = tid & 63, ln = lane & 15, quad = lane >> 4;
  const int qi = wave & 1, ki = wave >> 1;
  const int bh = blockIdx.y, b = bh >> 3, h = bh & 7;
  const int q0 = blockIdx.x * 64 + qi * 32;
  const int kbeg = ki * 1024, kend = kbeg + 1024;

  const unsigned short* Qhead = Qb + (size_t)bh * 2048 * 64;
  const unsigned short* Khead = Kb + (size_t)bh * 2048 * 64;
  const unsigned short* Vhead = Vtb + (size_t)bh * 64 * 2048;
  unsigned short* Ks = smem + ki * 4096;
  unsigned short* Vs = smem + 8192 + ki * 4096;

  // ---- DMA source mapping (per lane, k-invariant part) ----
  // LDS slot of lane lam within DMA j: s(row) = j*8 + (lane>>3), cpos = lane&7.
  // K: global row g = sigma^-1(s) (bits: g3=s2, g4=s3, g2=s4), chunk c = cpos ^ (s&7).
  // V: row d = s, chunk c = cpos ^ (d&7).  (s&7) == (lane>>3)&7 for all j.
  const int lah = lane >> 3, lam = lane & 7;
  const int cch = (lam ^ lah) * 8;           // chunk offset in shorts
  int srcK[8];                                // K row-part offsets (shorts)
  int srcV[8];                                // V row-part offsets (shorts)
#pragma unroll
  for (int j = 0; j < 8; ++j) {
    int s = j * 8 + lah;
    int g = (s & 0x23) | ((s & 4) << 1) | ((s & 8) << 1) | ((s & 16) >> 2);  // sigma^-1
    srcK[j] = g * 64 + cch;
    srcV[j] = s * 2048 + cch;
  }

  // Q B-frags (B[n=q][k=d]), loaded once
  bf16x8 qf[2][2];
#pragma unroll
  for (int ni2 = 0; ni2 < 2; ++ni2)
#pragma unroll
    for (int ks = 0; ks < 2; ++ks)
      qf[ni2][ks] = *(const bf16x8*)(Qhead + (size_t)(q0 + ni2 * 16 + ln) * 64 + ks * 32 + quad * 8);

  bf16x8 ones;
#pragma unroll
  for (int j = 0; j < 8; ++j) ones[j] = (short)0x3F80;

  floatx4 o[4][2];   // O^T: [d-tile][q-tile]
#pragma unroll
  for (int mi2 = 0; mi2 < 4; ++mi2)
#pragma unroll
    for (int ni2 = 0; ni2 < 2; ++ni2) o[mi2][ni2] = (floatx4){0.f, 0.f, 0.f, 0.f};
  floatx4 o5[2] = {(floatx4){0.f, 0.f, 0.f, 0.f}, (floatx4){0.f, 0.f, 0.f, 0.f}};
  float mrun[2] = {-INFINITY, -INFINITY};

  for (int k0 = kbeg; k0 < kend; k0 += 64) {
    __syncthreads();   // previous tile fully consumed
    if (qi == 0) {
      const unsigned short* kg = Khead + (size_t)k0 * 64;
#pragma unroll
      for (int j = 0; j < 8; ++j) gld_lds16(Ks + j * 512, kg + srcK[j]);
    } else {
      const unsigned short* vg = Vhead + k0;
#pragma unroll
      for (int j = 0; j < 8; ++j) gld_lds16(Vs + j * 512, vg + srcV[j]);
    }
    __syncthreads();   // DMA drained (vmcnt(0) before barrier), data visible

    // mask -> C-init at permuted row addresses (t_k = 32*(mi>>1)+4*(mi&1)+8*quad+r)
    floatx4 cini[4];
#pragma unroll
    for (int mi = 0; mi < 4; ++mi) {
      float4 mv = *(const float4*)(mask + b * 2048 + k0 + 32 * (mi >> 1) + 4 * (mi & 1) + 8 * quad);
      cini[mi] = (floatx4){mv.x * LOG2E, mv.y * LOG2E, mv.z * LOG2E, mv.w * LOG2E};
    }
    // S^T = K·Q^T from swizzled LDS
    floatx4 sm[4][2];
#pragma unroll
    for (int mi = 0; mi < 4; ++mi) {
      int row = mi * 16 + ln;
      bf16x8 kf0 = *(const bf16x8*)(Ks + row * 64 + ((quad ^ (ln & 7)) << 3));
      bf16x8 kf1 = *(const bf16x8*)(Ks + row * 64 + (((4 + quad) ^ (ln & 7)) << 3));
#pragma unroll
      for (int ni2 = 0; ni2 < 2; ++ni2) {
        floatx4 a = cini[mi];
        a = __builtin_amdgcn_mfma_f32_16x16x32_bf16(kf0, qf[ni2][0], a, 0, 0, 0);
        a = __builtin_amdgcn_mfma_f32_16x16x32_bf16(kf1, qf[ni2][1], a, 0, 0, 0);
        sm[mi][ni2] = a;
      }
    }
    // online softmax (per lane one q-col; combine quads with 2 shuffles)
    float alpha[2];
#pragma unroll
    for (int ni2 = 0; ni2 < 2; ++ni2) {
      float vmax = fmaxf(fmaxf(sm[0][ni2][0], sm[0][ni2][1]), fmaxf(sm[0][ni2][2], sm[0][ni2][3]));
#pragma unroll
      for (int mi = 1; mi < 4; ++mi)
        vmax = fmaxf(vmax, fmaxf(fmaxf(sm[mi][ni2][0], sm[mi][ni2][1]),
                                 fmaxf(sm[mi][ni2][2], sm[mi][ni2][3])));
      vmax = fmaxf(vmax, __shfl_xor(vmax, 16));
      vmax = fmaxf(vmax, __shfl_xor(vmax, 32));
      float nm = fmaxf(mrun[ni2], vmax);
      alpha[ni2] = exp2f(mrun[ni2] - nm);
      mrun[ni2] = nm;
    }
#pragma unroll
    for (int mi2 = 0; mi2 < 4; ++mi2)
#pragma unroll
      for (int ni2 = 0; ni2 < 2; ++ni2) {
        o[mi2][ni2][0] *= alpha[ni2]; o[mi2][ni2][1] *= alpha[ni2];
        o[mi2][ni2][2] *= alpha[ni2]; o[mi2][ni2][3] *= alpha[ni2];
      }
#pragma unroll
    for (int ni2 = 0; ni2 < 2; ++ni2) {
      o5[ni2][0] *= alpha[ni2]; o5[ni2][1] *= alpha[ni2];
      o5[ni2][2] *= alpha[ni2]; o5[ni2][3] *= alpha[ni2];
    }
    // p = exp2(s-m); pack straight into PV B-frags (tiles 2ks,2ks+1 -> one frag)
    bf16x8 pb[2][2];   // [ni2][ks]
#pragma unroll
    for (int ks = 0; ks < 2; ++ks)
#pragma unroll
      for (int ni2 = 0; ni2 < 2; ++ni2) {
        union { bf16x8 v; unsigned int u[4]; } pk;
        pk.u[0] = f2bf2(exp2f(sm[2 * ks][ni2][0] - mrun[ni2]), exp2f(sm[2 * ks][ni2][1] - mrun[ni2]));
        pk.u[1] = f2bf2(exp2f(sm[2 * ks][ni2][2] - mrun[ni2]), exp2f(sm[2 * ks][ni2][3] - mrun[ni2]));
        pk.u[2] = f2bf2(exp2f(sm[2 * ks + 1][ni2][0] - mrun[ni2]), exp2f(sm[2 * ks + 1][ni2][1] - mrun[ni2]));
        pk.u[3] = f2bf2(exp2f(sm[2 * ks + 1][ni2][2] - mrun[ni2]), exp2f(sm[2 * ks + 1][ni2][3] - mrun[ni2]));
        pb[ni2][ks] = pk.v;
      }
    // O^T += V^T·P ; l += ones·P
#pragma unroll
    for (int ks = 0; ks < 2; ++ks) {
#pragma unroll
      for (int mi2 = 0; mi2 < 4; ++mi2) {
        int row = mi2 * 16 + ln;
        bf16x8 vf = *(const bf16x8*)(Vs + row * 64 + (((ks * 4 + quad) ^ (ln & 7)) << 3));
#pragma unroll
        for (int ni2 = 0; ni2 < 2; ++ni2)
          o[mi2][ni2] = __builtin_amdgcn_mfma_f32_16x16x32_bf16(vf, pb[ni2][ks], o[mi2][ni2], 0, 0, 0);
      }
#pragma unroll
      for (int ni2 = 0; ni2 < 2; ++ni2)
        o5[ni2] = __builtin_amdgcn_mfma_f32_16x16x32_bf16(ones, pb[ni2][ks], o5[ni2], 0, 0, 0);
    }
  }

  // ---- split-K merge: ki=0 waves -> LDS scratch, ki=1 waves combine+store ----
  __syncthreads();                     // all staging-buffer reads done
  float* scr = (float*)smem;           // 2 waves x 64 lanes x 40 floats = 20 KB
  const int base = (qi * 64 + lane) * 40;
  if (ki == 0) {
#pragma unroll
    for (int mi2 = 0; mi2 < 4; ++mi2)
#pragma unroll
      for (int ni2 = 0; ni2 < 2; ++ni2)
        *(floatx4*)(scr + base + (mi2 * 2 + ni2) * 4) = o[mi2][ni2];
    scr[base + 32] = mrun[0];
    scr[base + 33] = mrun[1];
    scr[base + 34] = o5[0][0];
    scr[base + 35] = o5[1][0];
  }
  __syncthreads();
  if (ki == 1) {
#pragma unroll
    for (int ni2 = 0; ni2 < 2; ++ni2) {
      float m0s = scr[base + 32 + ni2];
      float l0s = scr[base + 34 + ni2];
      float M = fmaxf(m0s, mrun[ni2]);
      float c0 = exp2f(m0s - M);
      float c1 = exp2f(mrun[ni2] - M);
      float inv = 1.f / (l0s * c0 + o5[ni2][0] * c1);
      float ic0 = c0 * inv, ic1 = c1 * inv;
      int t = q0 + ni2 * 16 + ln;
      size_t obase = ((size_t)b * 2048 + t) * 512 + h * 64;
#pragma unroll
      for (int mi2 = 0; mi2 < 4; ++mi2) {
        floatx4 p0 = *(const floatx4*)(scr + base + (mi2 * 2 + ni2) * 4);
        unsigned int u0 = f2bf2(p0[0] * ic0 + o[mi2][ni2][0] * ic1,
                                p0[1] * ic0 + o[mi2][ni2][1] * ic1);
        unsigned int u1 = f2bf2(p0[2] * ic0 + o[mi2][ni2][2] * ic1,
                                p0[3] * ic0 + o[mi2][ni2][3] * ic1);
        *(uint2*)(attnb + obase + mi2 * 16 + quad * 4) = make_uint2(u0, u1);
      }
    }
  }
}

// ---------------------------------------------------------------------------
// proj GEMM (swapped operands), unchanged
// ---------------------------------------------------------------------------
__global__ __launch_bounds__(256) void proj_kernel(
    const unsigned short* __restrict__ ab, const unsigned short* __restrict__ wpb,
    const float* __restrict__ proj_b, float* __restrict__ out) {
  __shared__ __align__(16) unsigned short As[128 * 32];
  __shared__ __align__(16) unsigned short Bs[128 * 32];
  const int tid = threadIdx.x;
  const int wave = tid >> 6, lane = tid & 63, ln = lane & 15, quad = lane >> 4;
  const int m0 = blockIdx.x * 128, n0 = blockIdx.y * 128;
  const int wr = (wave >> 1) * 64, wc = (wave & 1) * 64;

  floatx4 acc[4][4];
#pragma unroll
  for (int i = 0; i < 4; ++i)
#pragma unroll
    for (int j = 0; j < 4; ++j) acc[i][j] = (floatx4){0.f, 0.f, 0.f, 0.f};

  const int c0 = tid, c1 = tid + 256;
  const int ar0 = c0 >> 2, ak0 = (c0 & 3) * 8;
  const int ar1 = c1 >> 2, ak1 = (c1 & 3) * 8;

  for (int k0 = 0; k0 < 512; k0 += 32) {
    __syncthreads();
    gld_lds16(As + c0 * 8, ab + (size_t)(m0 + ar0) * 512 + k0 + ak0);
    gld_lds16(As + c1 * 8, ab + (size_t)(m0 + ar1) * 512 + k0 + ak1);
    gld_lds16(Bs + c0 * 8, wpb + (size_t)(n0 + ar0) * 512 + k0 + ak0);
    gld_lds16(Bs + c1 * 8, wpb + (size_t)(n0 + ar1) * 512 + k0 + ak1);
    __syncthreads();
    bf16x8 af[4], bfb[4];
#pragma unroll
    for (int mi = 0; mi < 4; ++mi)
      af[mi] = *(const bf16x8*)(As + (wr + mi * 16 + ln) * 32 + quad * 8);
#pragma unroll
    for (int ni = 0; ni < 4; ++ni)
      bfb[ni] = *(const bf16x8*)(Bs + (wc + ni * 16 + ln) * 32 + quad * 8);
#pragma unroll
    for (int mi = 0; mi < 4; ++mi)
#pragma unroll
      for (int ni = 0; ni < 4; ++ni)
        acc[mi][ni] = __builtin_amdgcn_mfma_f32_16x16x32_bf16(bfb[mi], af[ni], acc[mi][ni], 0, 0, 0);
  }

  float4 bias4[4];
#pragma unroll
  for (int mi = 0; mi < 4; ++mi)
    bias4[mi] = *(const float4*)(proj_b + n0 + wc + mi * 16 + quad * 4);
#pragma unroll
  for (int ni = 0; ni < 4; ++ni) {
    int t = m0 + wr + ni * 16 + ln;
#pragma unroll
    for (int mi = 0; mi < 4; ++mi) {
      int col = n0 + wc + mi * 16 + quad * 4;
      float4 st;
      st.x = acc[mi][ni][0] + bias4[mi].x;
      st.y = acc[mi][ni][1] + bias4[mi].y;
      st.z = acc[mi][ni][2] + bias4[mi].z;
      st.w = acc[mi][ni][3] + bias4[mi].w;
      *(float4*)(out + (size_t)t * 512 + col) = st;
    }
  }
}

// ---------------------------------------------------------------------------
extern "C" void kernel_launch(void* const* d_in, const int* in_sizes, int n_in,
                              void* d_out, int out_size, void* d_ws, size_t ws_size,
                              hipStream_t stream) {
  const float* x      = (const float*)d_in[0];
  const float* mask   = (const float*)d_in[1];
  const float* qkv_w  = (const float*)d_in[2];
  const float* qkv_b  = (const float*)d_in[3];
  const float* proj_w = (const float*)d_in[4];
  const float* proj_b = (const float*)d_in[5];
  float* out = (float*)d_out;

  char* ws = (char*)d_ws;
  unsigned short* xb   = (unsigned short*)(ws);
  unsigned short* wqb  = (unsigned short*)(ws + 8388608);
  unsigned short* wpb  = (unsigned short*)(ws + 9961472);
  float* cosT          = (float*)(ws + 10485760);
  float* sinT          = (float*)(ws + 10747904);
  unsigned short* Qb   = (unsigned short*)(ws + 11010048);
  unsigned short* Kb   = (unsigned short*)(ws + 19398656);
  unsigned short* Vtb  = (unsigned short*)(ws + 27787264);
  unsigned short* attnb= (unsigned short*)(ws + 36175872);

  prep_kernel<<<20736, 256, 0, stream>>>(x, qkv_w, proj_w, xb, wqb, wpb, cosT, sinT);
  dim3 g1(64, 12);
  qkv_kernel<<<g1, 256, 0, stream>>>(xb, wqb, qkv_b, cosT, sinT, Qb, Kb, Vtb);
  dim3 g2(32, 32);
  attn_kernel<<<g2, 256, 0, stream>>>(Qb, Kb, Vtb, mask, attnb);
  dim3 g3(64, 4);
  proj_kernel<<<g3, 256, 0, stream>>>(attnb, wpb, proj_b, out);
}